// Round 2
// baseline (1157.403 us; speedup 1.0000x reference)
//
#include <hip/hip_runtime.h>
#include <stdint.h>

using bf16x8 = __attribute__((ext_vector_type(8))) short;
using f32x4  = __attribute__((ext_vector_type(4))) float;

__device__ __forceinline__ unsigned short f2bf(float f) {
  uint32_t x = __float_as_uint(f);
  x += 0x7fffu + ((x >> 16) & 1u);
  return (unsigned short)(x >> 16);
}
__device__ __forceinline__ float bf2f(unsigned short u) {
  return __uint_as_float(((uint32_t)u) << 16);
}
__device__ __forceinline__ float silu_f(float v) {
  return v / (1.0f + __expf(-v));
}

// ---- weight convert (f32 -> bf16 row-major [out][k]) + edge_index dtype sniff ----
__global__ void wconvert(const float* __restrict__ We1, const float* __restrict__ We2,
                         const float* __restrict__ Wn1, const float* __restrict__ Wn2,
                         const float* __restrict__ Wc1, const int* __restrict__ ei,
                         unsigned short* __restrict__ W1b, unsigned short* __restrict__ W2b,
                         unsigned short* __restrict__ N1b, unsigned short* __restrict__ N2b,
                         unsigned short* __restrict__ W3b, int* __restrict__ flag) {
  int i = blockIdx.x * 256 + threadIdx.x;      // 0..32767
  if (i < 128 * 256) {
    W1b[i] = f2bf(We1[(i >> 8) * 257 + (i & 255)]);   // We1 row stride 257; drop last col
    N1b[i] = f2bf(Wn1[i]);
  }
  if (i < 128 * 128) {
    W2b[i] = f2bf(We2[i]);
    W3b[i] = f2bf(Wc1[i]);
    N2b[i] = f2bf(Wn2[i]);
  }
  if (i == 0) {
    int allz = 1;
    for (int k = 0; k < 64; ++k) allz &= (ei[2 * k + 1] == 0);
    *flag = allz;   // 1 => indices are int64 (high words all zero)
  }
}

// ---- CSR build: histogram, single-block scan, scatter ----
__global__ void hist_kernel(const int* __restrict__ ei, const int* __restrict__ flag,
                            int* __restrict__ deg, int E) {
  int e = blockIdx.x * 256 + threadIdx.x;
  if (e >= E) return;
  int d = (*flag) ? (int)((const long long*)ei)[(size_t)E + e] : ei[E + e];
  atomicAdd(&deg[d], 1);
}

__global__ __launch_bounds__(1024) void scan_kernel(const int* __restrict__ deg,
                                                    int* __restrict__ offs,
                                                    int* __restrict__ cursor, int N) {
  __shared__ int part[1024];
  int t = threadIdx.x;
  int chunk = (N + 1023) / 1024;
  int s = 0;
  for (int i = 0; i < chunk; ++i) {
    int idx = t * chunk + i;
    if (idx < N) s += deg[idx];
  }
  part[t] = s;
  __syncthreads();
  for (int d = 1; d < 1024; d <<= 1) {
    int v = (t >= d) ? part[t - d] : 0;
    __syncthreads();
    part[t] += v;
    __syncthreads();
  }
  int run = (t == 0) ? 0 : part[t - 1];
  for (int i = 0; i < chunk; ++i) {
    int idx = t * chunk + i;
    if (idx < N) {
      offs[idx] = run; cursor[idx] = run;
      run += deg[idx];
    }
  }
  if (t == 0) offs[N] = part[1023];
}

__global__ void scatter_kernel(const int* __restrict__ ei, const int* __restrict__ flag,
                               int* __restrict__ cursor, int* __restrict__ csr_e, int E) {
  int e = blockIdx.x * 256 + threadIdx.x;
  if (e >= E) return;
  int d = (*flag) ? (int)((const long long*)ei)[(size_t)E + e] : ei[E + e];
  int pos = atomicAdd(&cursor[d], 1);
  csr_e[pos] = e;
}

// ---- shared GEMM micro-tile: wave computes 16 rows x 128 cols, K = KT*32 ----
template<int KT>
__device__ __forceinline__ void mm_tile(const unsigned short* A, int astr,
                                        const unsigned short* __restrict__ B, int bstr,
                                        int lg, int lr, f32x4 acc[8]) {
#pragma unroll
  for (int k0 = 0; k0 < KT; ++k0) {
    bf16x8 a = *(const bf16x8*)(A + lr * astr + k0 * 32 + lg * 8);
#pragma unroll
    for (int n = 0; n < 8; ++n) {
      bf16x8 b = *(const bf16x8*)(B + (size_t)(n * 16 + lr) * bstr + k0 * 32 + lg * 8);
      acc[n] = __builtin_amdgcn_mfma_f32_16x16x32_bf16(a, b, acc[n], 0, 0, 0);
    }
  }
}

// ---- fused edge kernel: 64 edges/block, 4 waves, each wave owns 16 edge rows ----
// MODE 0: atomic scatter (fallback).  MODE 1: CSR — coalesced m/cvec writes, no atomics.
template<int MODE>
__global__ __launch_bounds__(256) void edge_kernel(
    const float* __restrict__ h, const float* __restrict__ x, const int* __restrict__ ei,
    const float* __restrict__ We1, const float* __restrict__ be1,
    const float* __restrict__ be2, const float* __restrict__ bc1,
    const float* __restrict__ Wc2,
    const unsigned short* __restrict__ W1b, const unsigned short* __restrict__ W2b,
    const unsigned short* __restrict__ W3b,
    float* __restrict__ aggH, float* __restrict__ coordX, float* __restrict__ cnt,
    unsigned short* __restrict__ m_buf, float* __restrict__ cvec4,
    const int* __restrict__ flag, int E) {
  __shared__ __align__(16) unsigned short In[64][264];   // h_src|h_dst (K=256), reused as Ms2
  __shared__ __align__(16) unsigned short Ms[64][136];   // GEMM1 output
  __shared__ float sdif[64][3];
  __shared__ float sds[64];
  __shared__ int   ssrc[64], sdst[64];

  const int tid  = threadIdx.x;
  const int ebase = blockIdx.x * 64;
  const int w    = tid >> 6;
  const int lane = tid & 63;
  const int lg   = lane >> 4, lr = lane & 15;
  const int w16  = w * 16;

  if (tid < 64) {
    int e = ebase + tid;
    int s = 0, d = 0;
    if (e < E) {
      if (*flag) {
        s = (int)((const long long*)ei)[e];
        d = (int)((const long long*)ei)[(size_t)E + e];
      } else {
        s = ei[e];
        d = ei[E + e];
      }
    }
    ssrc[tid] = s; sdst[tid] = d;
    float dx = x[s * 3 + 0] - x[d * 3 + 0];
    float dy = x[s * 3 + 1] - x[d * 3 + 1];
    float dz = x[s * 3 + 2] - x[d * 3 + 2];
    sdif[tid][0] = dx; sdif[tid][1] = dy; sdif[tid][2] = dz;
    sds[tid] = dx * dx + dy * dy + dz * dz;
  }
  __syncthreads();

  // gather h[src]|h[dst] rows -> bf16 LDS
#pragma unroll
  for (int it = 0; it < 8; ++it) {
    int idx = tid + it * 256;            // 0..2047
    int e = idx >> 5, seg = idx & 31;    // 8-elem segment of the 256-wide row
    const float* p = (seg < 16) ? (h + (size_t)ssrc[e] * 128 + seg * 8)
                                : (h + (size_t)sdst[e] * 128 + (seg - 16) * 8);
    float4 a = *(const float4*)p;
    float4 b = *(const float4*)(p + 4);
    bf16x8 v;
    v[0] = f2bf(a.x); v[1] = f2bf(a.y); v[2] = f2bf(a.z); v[3] = f2bf(a.w);
    v[4] = f2bf(b.x); v[5] = f2bf(b.y); v[6] = f2bf(b.z); v[7] = f2bf(b.w);
    *(bf16x8*)&In[e][seg * 8] = v;
  }
  __syncthreads();

  // GEMM1: [64x256] x We1[:, :256]^T (+ be1 + ds*w1c), silu -> Ms
  {
    f32x4 acc[8];
#pragma unroll
    for (int n = 0; n < 8; ++n) { f32x4 z = {0.f, 0.f, 0.f, 0.f}; acc[n] = z; }
    mm_tile<8>(&In[w16][0], 264, W1b, 256, lg, lr, acc);
#pragma unroll
    for (int n = 0; n < 8; ++n) {
      int o = n * 16 + lr;
      float b1  = be1[o];
      float w1c = We1[o * 257 + 256];
#pragma unroll
      for (int r = 0; r < 4; ++r) {
        int me = lg * 4 + r;
        float v = acc[n][r] + b1 + sds[w16 + me] * w1c;
        Ms[w16 + me][o] = f2bf(silu_f(v));
      }
    }
  }

  // GEMM2: Ms x We2^T (+be2), silu -> Ms2 (reuses In arena, stride 264) [wave-local rows]
  unsigned short* Ms2 = &In[0][0];
  {
    f32x4 acc[8];
#pragma unroll
    for (int n = 0; n < 8; ++n) { f32x4 z = {0.f, 0.f, 0.f, 0.f}; acc[n] = z; }
    mm_tile<4>(&Ms[w16][0], 136, W2b, 128, lg, lr, acc);
#pragma unroll
    for (int n = 0; n < 8; ++n) {
      int o = n * 16 + lr;
      float b2 = be2[o];
#pragma unroll
      for (int r = 0; r < 4; ++r) {
        int me = w16 + lg * 4 + r;
        Ms2[(size_t)me * 264 + o] = f2bf(silu_f(acc[n][r] + b2));
      }
    }
  }

  // GEMM3: Ms2 x Wc1^T (+bc1), silu, dot with Wc2 -> cw
  {
    f32x4 acc[8];
#pragma unroll
    for (int n = 0; n < 8; ++n) { f32x4 z = {0.f, 0.f, 0.f, 0.f}; acc[n] = z; }
    mm_tile<4>(Ms2 + (size_t)w16 * 264, 264, W3b, 128, lg, lr, acc);
    float pr[4] = {0.f, 0.f, 0.f, 0.f};
#pragma unroll
    for (int n = 0; n < 8; ++n) {
      int o = n * 16 + lr;
      float b3 = bc1[o];
      float wc = Wc2[o];
#pragma unroll
      for (int r = 0; r < 4; ++r) pr[r] += silu_f(acc[n][r] + b3) * wc;
    }
#pragma unroll
    for (int m = 1; m < 16; m <<= 1) {
#pragma unroll
      for (int r = 0; r < 4; ++r) pr[r] += __shfl_xor(pr[r], m);
    }
#pragma unroll
    for (int r = 0; r < 4; ++r) {
      int me = w16 + lg * 4 + r;
      int eg = ebase + me;
      if (eg < E) {
        if (MODE == 0) {
          int d = sdst[me];
          if (lr < 3)       atomicAdd(&coordX[(size_t)d * 3 + lr], sdif[me][lr] * pr[r]);
          else if (lr == 3) atomicAdd(&cnt[d], 1.0f);
        } else {
          if (lr < 3) cvec4[(size_t)eg * 4 + lr] = sdif[me][lr] * pr[r];
        }
      }
    }
  }
  __syncthreads();

  if (MODE == 0) {
    // agg scatter: aggH[dst] += m2
#pragma unroll
    for (int it = 0; it < 32; ++it) {
      int idx = tid + it * 256;            // 0..8191
      int e = idx >> 7, c = idx & 127;
      int eg = ebase + e;
      if (eg < E) atomicAdd(&aggH[(size_t)sdst[e] * 128 + c], bf2f(Ms2[(size_t)e * 264 + c]));
    }
  } else {
    // coalesced m write-out: m_buf[e][0..127] bf16
#pragma unroll
    for (int it = 0; it < 4; ++it) {
      int idx = tid + it * 256;            // 0..1023
      int e = idx >> 4, seg = idx & 15;
      int eg = ebase + e;
      if (eg < E)
        *(bf16x8*)(m_buf + (size_t)eg * 128 + seg * 8) =
            *(const bf16x8*)&Ms2[(size_t)e * 264 + seg * 8];
    }
  }
}

// ---- wave-per-node CSR aggregation: sums m rows + coord contributions ----
__global__ __launch_bounds__(256) void agg_kernel(
    const unsigned short* __restrict__ m_buf, const float* __restrict__ cvec4,
    const int* __restrict__ offs, const int* __restrict__ csr_e,
    float* __restrict__ aggH, float* __restrict__ coordX, float* __restrict__ cntf, int N) {
  int wid  = (blockIdx.x * 256 + threadIdx.x) >> 6;   // node id
  int lane = threadIdx.x & 63;
  if (wid >= N) return;
  int beg = offs[wid], end = offs[wid + 1];
  int deg = end - beg;
  float a0 = 0.f, a1 = 0.f, c3 = 0.f;
  for (int b = 0; b < deg; b += 64) {
    int nb = min(64, deg - b);
    int id = (lane < nb) ? csr_e[beg + b + lane] : 0;
    for (int i = 0; i < nb; ++i) {
      int e = __shfl(id, i);
      uint32_t u = *(const uint32_t*)(m_buf + (size_t)e * 128 + lane * 2);
      a0 += bf2f((unsigned short)(u & 0xffffu));
      a1 += bf2f((unsigned short)(u >> 16));
      if (lane < 3) c3 += cvec4[(size_t)e * 4 + lane];
    }
  }
  aggH[(size_t)wid * 128 + lane * 2 + 0] = a0;
  aggH[(size_t)wid * 128 + lane * 2 + 1] = a1;
  if (lane < 3)  coordX[(size_t)wid * 3 + lane] = c3;
  if (lane == 0) cntf[wid] = (float)deg;
}

// ---- fused node kernel: 64 nodes/block; [h|agg/cnt] GEMM -> GEMM -> +h -> LN; x_out ----
__global__ __launch_bounds__(256) void node_kernel(
    const float* __restrict__ h, const float* __restrict__ x,
    const float* __restrict__ bn1, const float* __restrict__ bn2,
    const float* __restrict__ gamma, const float* __restrict__ beta,
    const unsigned short* __restrict__ N1b, const unsigned short* __restrict__ N2b,
    float* __restrict__ aggH, float* __restrict__ coordX,
    const float* __restrict__ cnt, int N) {
  __shared__ __align__(16) unsigned short In[64][264];   // [h|agg], reused as f32 hp[64][132]
  __shared__ __align__(16) unsigned short U[64][136];
  __shared__ float scnt[64];

  const int tid  = threadIdx.x;
  const int base = blockIdx.x * 64;
  const int w    = tid >> 6;
  const int lane = tid & 63;
  const int lg   = lane >> 4, lr = lane & 15;
  const int w16  = w * 16;

  if (tid < 64) {
    int n = base + tid;
    scnt[tid] = (n < N) ? fmaxf(cnt[n], 1.0f) : 1.0f;
  }
  __syncthreads();

#pragma unroll
  for (int it = 0; it < 8; ++it) {
    int idx = tid + it * 256;
    int i = idx >> 5, seg = idx & 31;
    int n = base + i; if (n >= N) n = N - 1;
    float sc = 1.0f;
    const float* p;
    if (seg < 16) { p = h + (size_t)n * 128 + seg * 8; }
    else          { p = aggH + (size_t)n * 128 + (seg - 16) * 8; sc = 1.0f / scnt[i]; }
    float4 a = *(const float4*)p;
    float4 b = *(const float4*)(p + 4);
    bf16x8 v;
    v[0] = f2bf(a.x * sc); v[1] = f2bf(a.y * sc); v[2] = f2bf(a.z * sc); v[3] = f2bf(a.w * sc);
    v[4] = f2bf(b.x * sc); v[5] = f2bf(b.y * sc); v[6] = f2bf(b.z * sc); v[7] = f2bf(b.w * sc);
    *(bf16x8*)&In[i][seg * 8] = v;
  }
  __syncthreads();

  // GEMM n1: [h|agg] x Wn1^T (+bn1), silu -> U
  {
    f32x4 acc[8];
#pragma unroll
    for (int n = 0; n < 8; ++n) { f32x4 z = {0.f, 0.f, 0.f, 0.f}; acc[n] = z; }
    mm_tile<8>(&In[w16][0], 264, N1b, 256, lg, lr, acc);
#pragma unroll
    for (int n = 0; n < 8; ++n) {
      int o = n * 16 + lr;
      float b1 = bn1[o];
#pragma unroll
      for (int r = 0; r < 4; ++r) {
        int me = lg * 4 + r;
        U[w16 + me][o] = f2bf(silu_f(acc[n][r] + b1));
      }
    }
  }

  // GEMM n2: U x Wn2^T (+bn2 +h) -> hp (f32, In arena) [wave-local rows]
  float* hp = (float*)&In[0][0];   // stride 132 f32 (row extent == 264 ushort)
  {
    f32x4 acc[8];
#pragma unroll
    for (int n = 0; n < 8; ++n) { f32x4 z = {0.f, 0.f, 0.f, 0.f}; acc[n] = z; }
    mm_tile<4>(&U[w16][0], 136, N2b, 128, lg, lr, acc);
#pragma unroll
    for (int n = 0; n < 8; ++n) {
      int o = n * 16 + lr;
      float b2 = bn2[o];
#pragma unroll
      for (int r = 0; r < 4; ++r) {
        int me = w16 + lg * 4 + r;
        int ng = base + me; if (ng >= N) ng = N - 1;
        hp[(size_t)me * 132 + o] = acc[n][r] + b2 + h[(size_t)ng * 128 + o];
      }
    }
  }
  __syncthreads();

  // LayerNorm: 4 threads per row
  {
    int r = tid >> 2, q = tid & 3;
    int ng = base + r;
    float s = 0.f, s2 = 0.f;
#pragma unroll
    for (int j = 0; j < 32; ++j) {
      float v = hp[(size_t)r * 132 + q * 32 + j];
      s += v; s2 += v * v;
    }
    s  += __shfl_xor(s, 1);  s  += __shfl_xor(s, 2);
    s2 += __shfl_xor(s2, 1); s2 += __shfl_xor(s2, 2);
    float mu  = s * (1.0f / 128.0f);
    float var = s2 * (1.0f / 128.0f) - mu * mu;
    float rs  = rsqrtf(var + 1e-5f);
    if (ng < N) {
#pragma unroll
      for (int j = 0; j < 32; ++j) {
        int o = q * 32 + j;
        float v = (hp[(size_t)r * 132 + o] - mu) * rs * gamma[o] + beta[o];
        aggH[(size_t)ng * 128 + o] = v;
      }
    }
  }

  // x_out = x + coord_agg / cnt   (in place over coord accumulator)
  if (tid < 192) {
    int i = tid / 3, c = tid % 3;
    int n2 = base + i;
    if (n2 < N) {
      size_t off = (size_t)n2 * 3 + c;
      coordX[off] = x[off] + coordX[off] / scnt[i];
    }
  }
}

extern "C" void kernel_launch(void* const* d_in, const int* in_sizes, int n_in,
                              void* d_out, int out_size, void* d_ws, size_t ws_size,
                              hipStream_t stream) {
  const float* h    = (const float*)d_in[0];
  const float* x    = (const float*)d_in[1];
  const int*   ei   = (const int*)d_in[2];
  const float* We1  = (const float*)d_in[3];
  const float* be1  = (const float*)d_in[4];
  const float* We2  = (const float*)d_in[5];
  const float* be2  = (const float*)d_in[6];
  const float* Wn1  = (const float*)d_in[7];
  const float* bn1  = (const float*)d_in[8];
  const float* Wn2  = (const float*)d_in[9];
  const float* bn2  = (const float*)d_in[10];
  const float* Wc1  = (const float*)d_in[11];
  const float* bc1  = (const float*)d_in[12];
  const float* Wc2  = (const float*)d_in[13];
  const float* gamma = (const float*)d_in[14];
  const float* beta  = (const float*)d_in[15];

  int N = in_sizes[0] / 128;
  int E = in_sizes[2] / 2;

  float* aggH   = (float*)d_out;                       // N*128: agg accumulator -> h_out
  float* coordX = (float*)d_out + (size_t)N * 128;     // N*3:   coord accumulator -> x_out

  char* ws = (char*)d_ws;
  size_t off = 0;
  auto alloc = [&](size_t bytes) {
    char* p = ws + off;
    off = (off + bytes + 255) & ~(size_t)255;
    return p;
  };
  float*          cnt    = (float*)alloc((size_t)N * 4);
  unsigned short* W1b    = (unsigned short*)alloc(128 * 256 * 2);
  unsigned short* W2b    = (unsigned short*)alloc(128 * 128 * 2);
  unsigned short* N1b    = (unsigned short*)alloc(128 * 256 * 2);
  unsigned short* N2b    = (unsigned short*)alloc(128 * 128 * 2);
  unsigned short* W3b    = (unsigned short*)alloc(128 * 128 * 2);
  int*            flag   = (int*)alloc(4);
  // CSR extras
  int*            deg    = (int*)alloc((size_t)N * 4);
  int*            offs   = (int*)alloc(((size_t)N + 1) * 4);
  int*            cursor = (int*)alloc((size_t)N * 4);
  int*            csr_e  = (int*)alloc((size_t)E * 4);
  float*          cvec4  = (float*)alloc((size_t)E * 16);
  unsigned short* m_buf  = (unsigned short*)alloc((size_t)E * 128 * 2);
  bool useCsr = (ws_size >= off);

  wconvert<<<128, 256, 0, stream>>>(We1, We2, Wn1, Wn2, Wc1, ei,
                                    W1b, W2b, N1b, N2b, W3b, flag);

  if (useCsr) {
    hipMemsetAsync(deg, 0, (size_t)N * 4, stream);
    hist_kernel<<<(E + 255) / 256, 256, 0, stream>>>(ei, flag, deg, E);
    scan_kernel<<<1, 1024, 0, stream>>>(deg, offs, cursor, N);
    scatter_kernel<<<(E + 255) / 256, 256, 0, stream>>>(ei, flag, cursor, csr_e, E);
    edge_kernel<1><<<(E + 63) / 64, 256, 0, stream>>>(h, x, ei, We1, be1, be2, bc1, Wc2,
                                                      W1b, W2b, W3b, aggH, coordX, cnt,
                                                      m_buf, cvec4, flag, E);
    agg_kernel<<<((N * 64) + 255) / 256, 256, 0, stream>>>(m_buf, cvec4, offs, csr_e,
                                                           aggH, coordX, cnt, N);
  } else {
    hipMemsetAsync(d_out, 0, (size_t)out_size * 4, stream);
    hipMemsetAsync(cnt, 0, (size_t)N * 4, stream);
    edge_kernel<0><<<(E + 63) / 64, 256, 0, stream>>>(h, x, ei, We1, be1, be2, bc1, Wc2,
                                                      W1b, W2b, W3b, aggH, coordX, cnt,
                                                      m_buf, cvec4, flag, E);
  }
  node_kernel<<<(N + 63) / 64, 256, 0, stream>>>(h, x, bn1, bn2, gamma, beta, N1b, N2b,
                                                 aggH, coordX, cnt, N);
}

// Round 3
// 612.336 us; speedup vs baseline: 1.8901x; 1.8901x over previous
//
#include <hip/hip_runtime.h>
#include <stdint.h>

using bf16x8 = __attribute__((ext_vector_type(8))) short;
using f32x4  = __attribute__((ext_vector_type(4))) float;

__device__ __forceinline__ unsigned short f2bf(float f) {
  uint32_t x = __float_as_uint(f);
  x += 0x7fffu + ((x >> 16) & 1u);
  return (unsigned short)(x >> 16);
}
__device__ __forceinline__ float bf2f(unsigned short u) {
  return __uint_as_float(((uint32_t)u) << 16);
}
__device__ __forceinline__ uint32_t cvtpk2(float lo, float hi) {
  uint32_t r;
  asm("v_cvt_pk_bf16_f32 %0, %1, %2" : "=v"(r) : "v"(lo), "v"(hi));
  return r;
}
__device__ __forceinline__ float silu_f(float v) {
  float e = __expf(-v);
  return v * __builtin_amdgcn_rcpf(1.0f + e);
}

// ---- prep: h -> bf16, weights -> bf16 row-major, edge_index dtype sniff ----
__global__ void prep_kernel(const float* __restrict__ h,
                            const float* __restrict__ We1, const float* __restrict__ We2,
                            const float* __restrict__ Wn1, const float* __restrict__ Wn2,
                            const float* __restrict__ Wc1, const int* __restrict__ ei,
                            unsigned short* __restrict__ h_bf,
                            unsigned short* __restrict__ W1b, unsigned short* __restrict__ W2b,
                            unsigned short* __restrict__ N1b, unsigned short* __restrict__ N2b,
                            unsigned short* __restrict__ W3b, int* __restrict__ flag,
                            int total) {
  int i = blockIdx.x * 256 + threadIdx.x;
  if (i < total) h_bf[i] = f2bf(h[i]);
  if (i < 128 * 256) {
    W1b[i] = f2bf(We1[(i >> 8) * 257 + (i & 255)]);   // drop last col (dist_sq weight)
    N1b[i] = f2bf(Wn1[i]);
  }
  if (i < 128 * 128) {
    W2b[i] = f2bf(We2[i]);
    W3b[i] = f2bf(Wc1[i]);
    N2b[i] = f2bf(Wn2[i]);
  }
  if (i == 0) {
    int allz = 1;
    for (int k = 0; k < 64; ++k) allz &= (ei[2 * k + 1] == 0);
    *flag = allz;   // 1 => int64 indices
  }
}

// ---- CSR build ----
__global__ void hist_kernel(const int* __restrict__ ei, const int* __restrict__ flag,
                            int* __restrict__ deg, int E) {
  int e = blockIdx.x * 256 + threadIdx.x;
  if (e >= E) return;
  int d = (*flag) ? (int)((const long long*)ei)[(size_t)E + e] : ei[E + e];
  atomicAdd(&deg[d], 1);
}

__global__ __launch_bounds__(1024) void scan_kernel(const int* __restrict__ deg,
                                                    int* __restrict__ offs,
                                                    int* __restrict__ cursor, int N) {
  __shared__ int part[1024];
  int t = threadIdx.x;
  int chunk = (N + 1023) / 1024;
  int s = 0;
  for (int i = 0; i < chunk; ++i) {
    int idx = t * chunk + i;
    if (idx < N) s += deg[idx];
  }
  part[t] = s;
  __syncthreads();
  for (int d = 1; d < 1024; d <<= 1) {
    int v = (t >= d) ? part[t - d] : 0;
    __syncthreads();
    part[t] += v;
    __syncthreads();
  }
  int run = (t == 0) ? 0 : part[t - 1];
  for (int i = 0; i < chunk; ++i) {
    int idx = t * chunk + i;
    if (idx < N) {
      offs[idx] = run; cursor[idx] = run;
      run += deg[idx];
    }
  }
  if (t == 0) offs[N] = part[1023];
}

__global__ void scatter_kernel(const int* __restrict__ ei, const int* __restrict__ flag,
                               int* __restrict__ cursor, int* __restrict__ csr_e, int E) {
  int e = blockIdx.x * 256 + threadIdx.x;
  if (e >= E) return;
  int d = (*flag) ? (int)((const long long*)ei)[(size_t)E + e] : ei[E + e];
  int pos = atomicAdd(&cursor[d], 1);
  csr_e[pos] = e;
}

// ---- fused edge kernel: 64 dst-sorted edges/block, col-split waves,
//      in-block segmented aggregation with few atomics ----
__global__ __launch_bounds__(256, 3) void edge_kernel(
    const unsigned short* __restrict__ h_bf, const float* __restrict__ x,
    const int* __restrict__ ei,
    const float* __restrict__ We1, const float* __restrict__ be1,
    const float* __restrict__ be2, const float* __restrict__ bc1,
    const float* __restrict__ Wc2,
    const unsigned short* __restrict__ W1b, const unsigned short* __restrict__ W2b,
    const unsigned short* __restrict__ W3b,
    float* __restrict__ aggH, float* __restrict__ coordX,
    const int* __restrict__ csr_e, const int* __restrict__ flag, int E) {
  __shared__ __align__(16) unsigned short In[64 * 264];   // [src|dst] K=256; reused as Ms2
  __shared__ __align__(16) unsigned short Ms[64 * 136];   // GEMM1 out; tail reused as swred
  __shared__ int   ssrc[64], sdst[64];
  __shared__ float sds[64];
  __shared__ float sdif[64][3];

  const int tid   = threadIdx.x;
  const int tbase = blockIdx.x * 64;
  const int w = tid >> 6, lane = tid & 63, lg = lane >> 4, lr = lane & 15;

  // indices + geometry (dst-sorted order via csr_e)
  if (tid < 64) {
    int pos = tbase + tid;
    int s = 0, d = 0;
    if (pos < E) {
      int eid = csr_e[pos];
      if (*flag) {
        s = (int)((const long long*)ei)[eid];
        d = (int)((const long long*)ei)[(size_t)E + eid];
      } else {
        s = ei[eid];
        d = ei[E + eid];
      }
    }
    ssrc[tid] = s; sdst[tid] = d;
    float dx = x[s * 3 + 0] - x[d * 3 + 0];
    float dy = x[s * 3 + 1] - x[d * 3 + 1];
    float dz = x[s * 3 + 2] - x[d * 3 + 2];
    sdif[tid][0] = dx; sdif[tid][1] = dy; sdif[tid][2] = dz;
    sds[tid] = dx * dx + dy * dy + dz * dz;
  }
  __syncthreads();

  // gather h_bf[src]|h_bf[dst] -> In (bf16, direct copy, all loads in flight)
  {
    uint4 v[8];
#pragma unroll
    for (int it = 0; it < 8; ++it) {
      int idx = tid + it * 256;
      int e = idx >> 5, c = idx & 31;
      int node = (c < 16) ? ssrc[e] : sdst[e];
      v[it] = *(const uint4*)(h_bf + (size_t)node * 128 + (c & 15) * 8);
    }
#pragma unroll
    for (int it = 0; it < 8; ++it) {
      int idx = tid + it * 256;
      int e = idx >> 5, c = idx & 31;
      *(uint4*)(&In[e * 264 + c * 8]) = v[it];
    }
  }
  __syncthreads();

  // ---- GEMM1: [64x256] @ We1^T, wave owns 64 rows x 32 cols ----
  {
    f32x4 acc[4][2];
#pragma unroll
    for (int m = 0; m < 4; ++m) { f32x4 z = {0.f,0.f,0.f,0.f}; acc[m][0] = z; acc[m][1] = z; }
#pragma unroll
    for (int k0 = 0; k0 < 8; ++k0) {
      bf16x8 b0 = *(const bf16x8*)(W1b + ((w * 32 + lr)      << 8) + k0 * 32 + lg * 8);
      bf16x8 b1 = *(const bf16x8*)(W1b + ((w * 32 + 16 + lr) << 8) + k0 * 32 + lg * 8);
#pragma unroll
      for (int m = 0; m < 4; ++m) {
        bf16x8 a = *(const bf16x8*)(&In[(m * 16 + lr) * 264 + k0 * 32 + lg * 8]);
        acc[m][0] = __builtin_amdgcn_mfma_f32_16x16x32_bf16(a, b0, acc[m][0], 0, 0, 0);
        acc[m][1] = __builtin_amdgcn_mfma_f32_16x16x32_bf16(a, b1, acc[m][1], 0, 0, 0);
      }
    }
#pragma unroll
    for (int n = 0; n < 2; ++n) {
      int o = w * 32 + n * 16 + lr;
      float b1v = be1[o];
      float w1c = We1[o * 257 + 256];
#pragma unroll
      for (int m = 0; m < 4; ++m) {
#pragma unroll
        for (int r = 0; r < 4; r += 2) {
          int row = m * 16 + lg * 4 + r;
          float v0 = acc[m][n][r]     + b1v + sds[row]     * w1c;
          float v1 = acc[m][n][r + 1] + b1v + sds[row + 1] * w1c;
          uint32_t u = cvtpk2(silu_f(v0), silu_f(v1));
          Ms[row * 136 + o]       = (unsigned short)(u & 0xffffu);
          Ms[(row + 1) * 136 + o] = (unsigned short)(u >> 16);
        }
      }
    }
  }
  __syncthreads();

  // ---- GEMM2: Ms @ We2^T -> Ms2 (In arena) ----
  {
    f32x4 acc[4][2];
#pragma unroll
    for (int m = 0; m < 4; ++m) { f32x4 z = {0.f,0.f,0.f,0.f}; acc[m][0] = z; acc[m][1] = z; }
#pragma unroll
    for (int k0 = 0; k0 < 4; ++k0) {
      bf16x8 b0 = *(const bf16x8*)(W2b + ((w * 32 + lr)      << 7) + k0 * 32 + lg * 8);
      bf16x8 b1 = *(const bf16x8*)(W2b + ((w * 32 + 16 + lr) << 7) + k0 * 32 + lg * 8);
#pragma unroll
      for (int m = 0; m < 4; ++m) {
        bf16x8 a = *(const bf16x8*)(&Ms[(m * 16 + lr) * 136 + k0 * 32 + lg * 8]);
        acc[m][0] = __builtin_amdgcn_mfma_f32_16x16x32_bf16(a, b0, acc[m][0], 0, 0, 0);
        acc[m][1] = __builtin_amdgcn_mfma_f32_16x16x32_bf16(a, b1, acc[m][1], 0, 0, 0);
      }
    }
#pragma unroll
    for (int n = 0; n < 2; ++n) {
      int o = w * 32 + n * 16 + lr;
      float b2v = be2[o];
#pragma unroll
      for (int m = 0; m < 4; ++m) {
#pragma unroll
        for (int r = 0; r < 4; r += 2) {
          int row = m * 16 + lg * 4 + r;
          uint32_t u = cvtpk2(silu_f(acc[m][n][r] + b2v), silu_f(acc[m][n][r + 1] + b2v));
          In[row * 264 + o]       = (unsigned short)(u & 0xffffu);
          In[(row + 1) * 264 + o] = (unsigned short)(u >> 16);
        }
      }
    }
  }
  __syncthreads();

  // ---- GEMM3: Ms2 @ Wc1^T, silu, dot Wc2 -> per-edge cw partials in swred ----
  {
    f32x4 acc[4][2];
#pragma unroll
    for (int m = 0; m < 4; ++m) { f32x4 z = {0.f,0.f,0.f,0.f}; acc[m][0] = z; acc[m][1] = z; }
#pragma unroll
    for (int k0 = 0; k0 < 4; ++k0) {
      bf16x8 b0 = *(const bf16x8*)(W3b + ((w * 32 + lr)      << 7) + k0 * 32 + lg * 8);
      bf16x8 b1 = *(const bf16x8*)(W3b + ((w * 32 + 16 + lr) << 7) + k0 * 32 + lg * 8);
#pragma unroll
      for (int m = 0; m < 4; ++m) {
        bf16x8 a = *(const bf16x8*)(&In[(m * 16 + lr) * 264 + k0 * 32 + lg * 8]);
        acc[m][0] = __builtin_amdgcn_mfma_f32_16x16x32_bf16(a, b0, acc[m][0], 0, 0, 0);
        acc[m][1] = __builtin_amdgcn_mfma_f32_16x16x32_bf16(a, b1, acc[m][1], 0, 0, 0);
      }
    }
    float pr[4][4];
#pragma unroll
    for (int m = 0; m < 4; ++m)
#pragma unroll
      for (int r = 0; r < 4; ++r) pr[m][r] = 0.f;
#pragma unroll
    for (int n = 0; n < 2; ++n) {
      int o = w * 32 + n * 16 + lr;
      float b3 = bc1[o], wc = Wc2[o];
#pragma unroll
      for (int m = 0; m < 4; ++m)
#pragma unroll
        for (int r = 0; r < 4; ++r)
          pr[m][r] += silu_f(acc[m][n][r] + b3) * wc;
    }
#pragma unroll
    for (int m = 0; m < 4; ++m)
#pragma unroll
      for (int r = 0; r < 4; ++r) {
        float v = pr[m][r];
        v += __shfl_xor(v, 1); v += __shfl_xor(v, 2);
        v += __shfl_xor(v, 4); v += __shfl_xor(v, 8);
        pr[m][r] = v;
      }
    float* swredf = (float*)&Ms[0];   // Ms arena dead after GEMM2
    if (lr == 0) {
#pragma unroll
      for (int m = 0; m < 4; ++m)
#pragma unroll
        for (int r = 0; r < 4; ++r)
          swredf[w * 64 + m * 16 + lg * 4 + r] = pr[m][r];
    }
  }
  __syncthreads();

  // ---- segmented aggregation (edges dst-sorted): few atomics per block ----
  const int nv = min(64, E - tbase);
  {
    int c = tid & 127, hf = tid >> 7;
    int e0 = hf * 32;
    int nvh = min(32, nv - e0);
    if (nvh > 0) {
      float run = 0.f;
      int prev = sdst[e0];
#pragma unroll 4
      for (int j = 0; j < nvh; ++j) {
        int e = e0 + j;
        int d = sdst[e];
        float v = bf2f(In[e * 264 + c]);
        if (d != prev) {
          atomicAdd(&aggH[(size_t)prev * 128 + c], run);
          run = 0.f; prev = d;
        }
        run += v;
      }
      atomicAdd(&aggH[(size_t)prev * 128 + c], run);
    }
  }
  if (tid < 6) {
    const float* swredf = (const float*)&Ms[0];
    int c3 = tid % 3, hf = tid / 3;
    int e0 = hf * 32;
    int nvh = min(32, nv - e0);
    if (nvh > 0) {
      float run = 0.f;
      int prev = sdst[e0];
#pragma unroll 4
      for (int j = 0; j < nvh; ++j) {
        int e = e0 + j;
        int d = sdst[e];
        float cwv = swredf[e] + swredf[64 + e] + swredf[128 + e] + swredf[192 + e];
        if (d != prev) {
          atomicAdd(&coordX[(size_t)prev * 3 + c3], run);
          run = 0.f; prev = d;
        }
        run += sdif[e][c3] * cwv;
      }
      atomicAdd(&coordX[(size_t)prev * 3 + c3], run);
    }
  }
}

// ---- fused node kernel: 64 nodes/block; [h|agg/deg] GEMM -> GEMM -> +h -> LN; x_out ----
__global__ __launch_bounds__(256) void node_kernel(
    const float* __restrict__ h, const float* __restrict__ x,
    const float* __restrict__ bn1, const float* __restrict__ bn2,
    const float* __restrict__ gamma, const float* __restrict__ beta,
    const unsigned short* __restrict__ N1b, const unsigned short* __restrict__ N2b,
    float* __restrict__ aggH, float* __restrict__ coordX,
    const int* __restrict__ deg, int N) {
  __shared__ __align__(16) unsigned short In[64][264];   // [h|agg], reused as f32 hp[64][132]
  __shared__ __align__(16) unsigned short U[64][136];
  __shared__ float scnt[64];

  const int tid  = threadIdx.x;
  const int base = blockIdx.x * 64;
  const int w    = tid >> 6;
  const int lane = tid & 63;
  const int lg   = lane >> 4, lr = lane & 15;
  const int w16  = w * 16;

  if (tid < 64) {
    int n = base + tid;
    scnt[tid] = (n < N) ? fmaxf((float)deg[n], 1.0f) : 1.0f;
  }
  __syncthreads();

#pragma unroll
  for (int it = 0; it < 8; ++it) {
    int idx = tid + it * 256;
    int i = idx >> 5, seg = idx & 31;
    int n = base + i; if (n >= N) n = N - 1;
    float sc = 1.0f;
    const float* p;
    if (seg < 16) { p = h + (size_t)n * 128 + seg * 8; }
    else          { p = aggH + (size_t)n * 128 + (seg - 16) * 8; sc = 1.0f / scnt[i]; }
    float4 a = *(const float4*)p;
    float4 b = *(const float4*)(p + 4);
    uint32_t u0 = cvtpk2(a.x * sc, a.y * sc);
    uint32_t u1 = cvtpk2(a.z * sc, a.w * sc);
    uint32_t u2 = cvtpk2(b.x * sc, b.y * sc);
    uint32_t u3 = cvtpk2(b.z * sc, b.w * sc);
    uint4 v = {u0, u1, u2, u3};
    *(uint4*)&In[i][seg * 8] = v;
  }
  __syncthreads();

  // GEMM n1: [h|agg] @ Wn1^T (+bn1), silu -> U
  {
    f32x4 acc[8];
#pragma unroll
    for (int n = 0; n < 8; ++n) { f32x4 z = {0.f,0.f,0.f,0.f}; acc[n] = z; }
#pragma unroll
    for (int k0 = 0; k0 < 8; ++k0) {
      bf16x8 a = *(const bf16x8*)(&In[w16 + lr][k0 * 32 + lg * 8]);
#pragma unroll
      for (int n = 0; n < 8; ++n) {
        bf16x8 b = *(const bf16x8*)(N1b + ((n * 16 + lr) << 8) + k0 * 32 + lg * 8);
        acc[n] = __builtin_amdgcn_mfma_f32_16x16x32_bf16(a, b, acc[n], 0, 0, 0);
      }
    }
#pragma unroll
    for (int n = 0; n < 8; ++n) {
      int o = n * 16 + lr;
      float b1 = bn1[o];
#pragma unroll
      for (int r = 0; r < 4; ++r) {
        int me = lg * 4 + r;
        U[w16 + me][o] = f2bf(silu_f(acc[n][r] + b1));
      }
    }
  }

  // GEMM n2: U @ Wn2^T (+bn2 +h) -> hp (f32, In arena) [wave-local rows]
  float* hp = (float*)&In[0][0];   // stride 132 f32
  {
    f32x4 acc[8];
#pragma unroll
    for (int n = 0; n < 8; ++n) { f32x4 z = {0.f,0.f,0.f,0.f}; acc[n] = z; }
#pragma unroll
    for (int k0 = 0; k0 < 4; ++k0) {
      bf16x8 a = *(const bf16x8*)(&U[w16 + lr][k0 * 32 + lg * 8]);
#pragma unroll
      for (int n = 0; n < 8; ++n) {
        bf16x8 b = *(const bf16x8*)(N2b + ((n * 16 + lr) << 7) + k0 * 32 + lg * 8);
        acc[n] = __builtin_amdgcn_mfma_f32_16x16x32_bf16(a, b, acc[n], 0, 0, 0);
      }
    }
#pragma unroll
    for (int n = 0; n < 8; ++n) {
      int o = n * 16 + lr;
      float b2 = bn2[o];
#pragma unroll
      for (int r = 0; r < 4; ++r) {
        int me = w16 + lg * 4 + r;
        int ng = base + me; if (ng >= N) ng = N - 1;
        hp[(size_t)me * 132 + o] = acc[n][r] + b2 + h[(size_t)ng * 128 + o];
      }
    }
  }
  __syncthreads();

  // LayerNorm: 4 threads per row
  {
    int r = tid >> 2, q = tid & 3;
    int ng = base + r;
    float s = 0.f, s2 = 0.f;
#pragma unroll
    for (int j = 0; j < 32; ++j) {
      float v = hp[(size_t)r * 132 + q * 32 + j];
      s += v; s2 += v * v;
    }
    s  += __shfl_xor(s, 1);  s  += __shfl_xor(s, 2);
    s2 += __shfl_xor(s2, 1); s2 += __shfl_xor(s2, 2);
    float mu  = s * (1.0f / 128.0f);
    float var = s2 * (1.0f / 128.0f) - mu * mu;
    float rs  = rsqrtf(var + 1e-5f);
    if (ng < N) {
#pragma unroll
      for (int j = 0; j < 32; ++j) {
        int o = q * 32 + j;
        float v = (hp[(size_t)r * 132 + o] - mu) * rs * gamma[o] + beta[o];
        aggH[(size_t)ng * 128 + o] = v;
      }
    }
  }

  // x_out = x + coord_agg / cnt
  if (tid < 192) {
    int i = tid / 3, c = tid % 3;
    int n2 = base + i;
    if (n2 < N) {
      size_t off = (size_t)n2 * 3 + c;
      coordX[off] = x[off] + coordX[off] / scnt[i];
    }
  }
}

extern "C" void kernel_launch(void* const* d_in, const int* in_sizes, int n_in,
                              void* d_out, int out_size, void* d_ws, size_t ws_size,
                              hipStream_t stream) {
  const float* h    = (const float*)d_in[0];
  const float* x    = (const float*)d_in[1];
  const int*   ei   = (const int*)d_in[2];
  const float* We1  = (const float*)d_in[3];
  const float* be1  = (const float*)d_in[4];
  const float* We2  = (const float*)d_in[5];
  const float* be2  = (const float*)d_in[6];
  const float* Wn1  = (const float*)d_in[7];
  const float* bn1  = (const float*)d_in[8];
  const float* Wn2  = (const float*)d_in[9];
  const float* bn2  = (const float*)d_in[10];
  const float* Wc1  = (const float*)d_in[11];
  const float* bc1  = (const float*)d_in[12];
  const float* Wc2  = (const float*)d_in[13];
  const float* gamma = (const float*)d_in[14];
  const float* beta  = (const float*)d_in[15];

  int N = in_sizes[0] / 128;
  int E = in_sizes[2] / 2;

  float* aggH   = (float*)d_out;                       // N*128: agg accumulator -> h_out
  float* coordX = (float*)d_out + (size_t)N * 128;     // N*3:   coord accumulator -> x_out

  char* ws = (char*)d_ws;
  size_t off = 0;
  auto alloc = [&](size_t bytes) {
    char* p = ws + off;
    off = (off + bytes + 255) & ~(size_t)255;
    return p;
  };
  unsigned short* h_bf   = (unsigned short*)alloc((size_t)N * 128 * 2);
  unsigned short* W1b    = (unsigned short*)alloc(128 * 256 * 2);
  unsigned short* W2b    = (unsigned short*)alloc(128 * 128 * 2);
  unsigned short* N1b    = (unsigned short*)alloc(128 * 256 * 2);
  unsigned short* N2b    = (unsigned short*)alloc(128 * 128 * 2);
  unsigned short* W3b    = (unsigned short*)alloc(128 * 128 * 2);
  int*            flag   = (int*)alloc(4);
  int*            deg    = (int*)alloc((size_t)N * 4);
  int*            offs   = (int*)alloc(((size_t)N + 1) * 4);
  int*            cursor = (int*)alloc((size_t)N * 4);
  int*            csr_e  = (int*)alloc((size_t)E * 4);
  (void)ws_size;

  int total = N * 128;
  int ntiles = (E + 63) / 64;

  hipMemsetAsync(d_out, 0, (size_t)out_size * 4, stream);
  hipMemsetAsync(deg, 0, (size_t)N * 4, stream);

  prep_kernel<<<(total + 255) / 256, 256, 0, stream>>>(h, We1, We2, Wn1, Wn2, Wc1, ei,
                                                       h_bf, W1b, W2b, N1b, N2b, W3b, flag,
                                                       total);
  hist_kernel<<<(E + 255) / 256, 256, 0, stream>>>(ei, flag, deg, E);
  scan_kernel<<<1, 1024, 0, stream>>>(deg, offs, cursor, N);
  scatter_kernel<<<(E + 255) / 256, 256, 0, stream>>>(ei, flag, cursor, csr_e, E);
  edge_kernel<<<ntiles, 256, 0, stream>>>(h_bf, x, ei, We1, be1, be2, bc1, Wc2,
                                          W1b, W2b, W3b, aggH, coordX, csr_e, flag, E);
  node_kernel<<<(N + 63) / 64, 256, 0, stream>>>(h, x, bn1, bn2, gamma, beta, N1b, N2b,
                                                 aggH, coordX, deg, N);
}

// Round 4
// 604.033 us; speedup vs baseline: 1.9161x; 1.0137x over previous
//
#include <hip/hip_runtime.h>
#include <stdint.h>

using bf16x8 = __attribute__((ext_vector_type(8))) short;
using f32x4  = __attribute__((ext_vector_type(4))) float;

__device__ __forceinline__ unsigned short f2bf(float f) {
  uint32_t x = __float_as_uint(f);
  x += 0x7fffu + ((x >> 16) & 1u);
  return (unsigned short)(x >> 16);
}
__device__ __forceinline__ float bf2f(unsigned short u) {
  return __uint_as_float(((uint32_t)u) << 16);
}
__device__ __forceinline__ uint32_t cvtpk2(float lo, float hi) {
  uint32_t r;
  asm("v_cvt_pk_bf16_f32 %0, %1, %2" : "=v"(r) : "v"(lo), "v"(hi));
  return r;
}
__device__ __forceinline__ float silu_f(float v) {
  float e = __expf(-v);
  return v * __builtin_amdgcn_rcpf(1.0f + e);
}

// Ms rotated-swizzle addressing: row stride 136 ushort (272B, b128-aligned).
// 16B slot s of row -> slot' = (s + 4*row) & 15  => ds_read_b128 bank-quad
// = (5*lr + s) mod 8, a permutation in lr => conflict-free (2-way max).
__device__ __forceinline__ int msoff(int row, int col) {
  return row * 136 + ((((col >> 3) + row * 4) & 15) << 3) + (col & 7);
}
__device__ __forceinline__ int msoff_slot(int row, int slot) {
  return row * 136 + (((slot + row * 4) & 15) << 3);
}

// ---- prep: h -> bf16, weights -> bf16 row-major, edge_index dtype sniff ----
__global__ void prep_kernel(const float* __restrict__ h,
                            const float* __restrict__ We1, const float* __restrict__ We2,
                            const float* __restrict__ Wn1, const float* __restrict__ Wn2,
                            const float* __restrict__ Wc1, const int* __restrict__ ei,
                            unsigned short* __restrict__ h_bf,
                            unsigned short* __restrict__ W1b, unsigned short* __restrict__ W2b,
                            unsigned short* __restrict__ N1b, unsigned short* __restrict__ N2b,
                            unsigned short* __restrict__ W3b, int* __restrict__ flag,
                            int total) {
  int i = blockIdx.x * 256 + threadIdx.x;
  if (i < total) h_bf[i] = f2bf(h[i]);
  if (i < 128 * 256) {
    W1b[i] = f2bf(We1[(i >> 8) * 257 + (i & 255)]);   // drop last col (dist_sq weight)
    N1b[i] = f2bf(Wn1[i]);
  }
  if (i < 128 * 128) {
    W2b[i] = f2bf(We2[i]);
    W3b[i] = f2bf(Wc1[i]);
    N2b[i] = f2bf(Wn2[i]);
  }
  if (i == 0) {
    int allz = 1;
    for (int k = 0; k < 64; ++k) allz &= (ei[2 * k + 1] == 0);
    *flag = allz;   // 1 => int64 indices
  }
}

// ---- CSR-order build: hist + 3-kernel parallel scan + scatter ----
__global__ void hist_kernel(const int* __restrict__ ei, const int* __restrict__ flag,
                            int* __restrict__ deg, int E) {
  int e = blockIdx.x * 256 + threadIdx.x;
  if (e >= E) return;
  int d = (*flag) ? (int)((const long long*)ei)[(size_t)E + e] : ei[E + e];
  atomicAdd(&deg[d], 1);
}

__global__ void scanA_kernel(const int* __restrict__ deg, int* __restrict__ offs,
                             int* __restrict__ bsum, int N) {
  __shared__ int sh[256];
  int t = threadIdx.x, idx = blockIdx.x * 256 + t;
  int v = (idx < N) ? deg[idx] : 0;
  sh[t] = v;
  __syncthreads();
#pragma unroll
  for (int d = 1; d < 256; d <<= 1) {
    int u = (t >= d) ? sh[t - d] : 0;
    __syncthreads();
    sh[t] += u;
    __syncthreads();
  }
  if (idx < N) offs[idx] = sh[t] - v;       // block-local exclusive
  if (t == 255) bsum[blockIdx.x] = sh[255];
}

__global__ void scanB_kernel(int* __restrict__ bsum, int* __restrict__ offs,
                             int nb, int N) {   // 1 block, 256 threads
  __shared__ int sh[256];
  int t = threadIdx.x;
  int v = (t < nb) ? bsum[t] : 0;
  sh[t] = v;
  __syncthreads();
#pragma unroll
  for (int d = 1; d < 256; d <<= 1) {
    int u = (t >= d) ? sh[t - d] : 0;
    __syncthreads();
    sh[t] += u;
    __syncthreads();
  }
  bsum[t] = sh[t] - v;                      // exclusive block offsets
  if (t == 255) offs[N] = sh[255];
}

__global__ void scanC_kernel(const int* __restrict__ bsum, int* __restrict__ offs,
                             int* __restrict__ cursor, int N) {
  int idx = blockIdx.x * 256 + threadIdx.x;
  if (idx < N) {
    int o = offs[idx] + bsum[blockIdx.x];
    offs[idx] = o;
    cursor[idx] = o;
  }
}

__global__ void scatter_kernel(const int* __restrict__ ei, const int* __restrict__ flag,
                               int* __restrict__ cursor, int* __restrict__ csr_e, int E) {
  int e = blockIdx.x * 256 + threadIdx.x;
  if (e >= E) return;
  int d = (*flag) ? (int)((const long long*)ei)[(size_t)E + e] : ei[E + e];
  int pos = atomicAdd(&cursor[d], 1);
  csr_e[pos] = e;
}

// ---- fused edge kernel: 64 dst-sorted edges/block; A-from-global GEMM1;
//      Ms-only LDS (19KB) -> ~6 blocks/CU; segmented aggregation ----
__global__ __launch_bounds__(256, 6) void edge_kernel(
    const unsigned short* __restrict__ h_bf, const float* __restrict__ x,
    const int* __restrict__ ei,
    const float* __restrict__ We1, const float* __restrict__ be1,
    const float* __restrict__ be2, const float* __restrict__ bc1,
    const float* __restrict__ Wc2,
    const unsigned short* __restrict__ W1b, const unsigned short* __restrict__ W2b,
    const unsigned short* __restrict__ W3b,
    float* __restrict__ aggH, float* __restrict__ coordX,
    const int* __restrict__ csr_e, const int* __restrict__ flag, int E) {
  __shared__ __align__(16) unsigned short Ms[64 * 136];  // GEMM1 out, then Ms2
  __shared__ float swred[4][64];
  __shared__ int   ssrc[64], sdst[64];
  __shared__ float sds[64];
  __shared__ float sdif[64][3];

  const int tid   = threadIdx.x;
  const int tbase = blockIdx.x * 64;
  const int w = tid >> 6, lane = tid & 63, lg = lane >> 4, lr = lane & 15;

  // phase 0: indices + geometry (dst-sorted order via csr_e)
  if (tid < 64) {
    int pos = tbase + tid;
    int s = 0, d = 0;
    if (pos < E) {
      int eid = csr_e[pos];
      if (*flag) {
        s = (int)((const long long*)ei)[eid];
        d = (int)((const long long*)ei)[(size_t)E + eid];
      } else {
        s = ei[eid];
        d = ei[E + eid];
      }
    }
    ssrc[tid] = s; sdst[tid] = d;
    float dx = x[s * 3 + 0] - x[d * 3 + 0];
    float dy = x[s * 3 + 1] - x[d * 3 + 1];
    float dz = x[s * 3 + 2] - x[d * 3 + 2];
    sdif[tid][0] = dx; sdif[tid][1] = dy; sdif[tid][2] = dz;
    sds[tid] = dx * dx + dy * dy + dz * dz;
  }
  __syncthreads();

  // per-lane byte offsets into h_bf for the 8 A-rows this lane reads
  uint32_t offs_s[4], offs_d[4];
#pragma unroll
  for (int m = 0; m < 4; ++m) {
    offs_s[m] = ((uint32_t)ssrc[m * 16 + lr] << 8) + lg * 16;   // node*256B + lg*16B
    offs_d[m] = ((uint32_t)sdst[m * 16 + lr] << 8) + lg * 16;
  }
  const char* hb = (const char*)h_bf;

  // ---- GEMM1: [64x256] @ We1^T, A per-lane from GLOBAL, wave owns 32 cols ----
  {
    f32x4 acc[4][2];
#pragma unroll
    for (int m = 0; m < 4; ++m) { f32x4 z = {0.f,0.f,0.f,0.f}; acc[m][0] = z; acc[m][1] = z; }
#pragma unroll
    for (int k0 = 0; k0 < 8; ++k0) {
      bf16x8 b0 = *(const bf16x8*)(W1b + ((w * 32 + lr)      << 8) + k0 * 32 + lg * 8);
      bf16x8 b1 = *(const bf16x8*)(W1b + ((w * 32 + 16 + lr) << 8) + k0 * 32 + lg * 8);
#pragma unroll
      for (int m = 0; m < 4; ++m) {
        bf16x8 a = (k0 < 4)
            ? *(const bf16x8*)(hb + offs_s[m] + k0 * 64)
            : *(const bf16x8*)(hb + offs_d[m] + (k0 - 4) * 64);
        acc[m][0] = __builtin_amdgcn_mfma_f32_16x16x32_bf16(a, b0, acc[m][0], 0, 0, 0);
        acc[m][1] = __builtin_amdgcn_mfma_f32_16x16x32_bf16(a, b1, acc[m][1], 0, 0, 0);
      }
    }
#pragma unroll
    for (int n = 0; n < 2; ++n) {
      int o = w * 32 + n * 16 + lr;
      float b1v = be1[o];
      float w1c = We1[o * 257 + 256];
#pragma unroll
      for (int m = 0; m < 4; ++m) {
#pragma unroll
        for (int r = 0; r < 4; r += 2) {
          int row = m * 16 + lg * 4 + r;
          float v0 = acc[m][n][r]     + b1v + sds[row]     * w1c;
          float v1 = acc[m][n][r + 1] + b1v + sds[row + 1] * w1c;
          uint32_t u = cvtpk2(silu_f(v0), silu_f(v1));
          Ms[msoff(row, o)]     = (unsigned short)(u & 0xffffu);
          Ms[msoff(row + 1, o)] = (unsigned short)(u >> 16);
        }
      }
    }
  }
  __syncthreads();

  // ---- GEMM2: Ms @ We2^T -> Ms2 (same arena; read-all / barrier / write-all) ----
  {
    f32x4 acc[4][2];
#pragma unroll
    for (int m = 0; m < 4; ++m) { f32x4 z = {0.f,0.f,0.f,0.f}; acc[m][0] = z; acc[m][1] = z; }
#pragma unroll
    for (int k0 = 0; k0 < 4; ++k0) {
      bf16x8 b0 = *(const bf16x8*)(W2b + ((w * 32 + lr)      << 7) + k0 * 32 + lg * 8);
      bf16x8 b1 = *(const bf16x8*)(W2b + ((w * 32 + 16 + lr) << 7) + k0 * 32 + lg * 8);
#pragma unroll
      for (int m = 0; m < 4; ++m) {
        int row = m * 16 + lr;
        bf16x8 a = *(const bf16x8*)(&Ms[msoff_slot(row, k0 * 4 + lg)]);
        acc[m][0] = __builtin_amdgcn_mfma_f32_16x16x32_bf16(a, b0, acc[m][0], 0, 0, 0);
        acc[m][1] = __builtin_amdgcn_mfma_f32_16x16x32_bf16(a, b1, acc[m][1], 0, 0, 0);
      }
    }
    uint32_t pk[4][2][2];
#pragma unroll
    for (int n = 0; n < 2; ++n) {
      int o = w * 32 + n * 16 + lr;
      float b2v = be2[o];
#pragma unroll
      for (int m = 0; m < 4; ++m)
#pragma unroll
        for (int r = 0; r < 4; r += 2)
          pk[m][n][r >> 1] = cvtpk2(silu_f(acc[m][n][r] + b2v),
                                    silu_f(acc[m][n][r + 1] + b2v));
    }
    __syncthreads();   // all waves done READING Ms
#pragma unroll
    for (int n = 0; n < 2; ++n) {
      int o = w * 32 + n * 16 + lr;
#pragma unroll
      for (int m = 0; m < 4; ++m)
#pragma unroll
        for (int r = 0; r < 4; r += 2) {
          int row = m * 16 + lg * 4 + r;
          uint32_t u = pk[m][n][r >> 1];
          Ms[msoff(row, o)]     = (unsigned short)(u & 0xffffu);
          Ms[msoff(row + 1, o)] = (unsigned short)(u >> 16);
        }
    }
  }
  __syncthreads();

  // ---- GEMM3: Ms2 @ Wc1^T, silu, dot Wc2 -> swred[w][edge] ----
  {
    f32x4 acc[4][2];
#pragma unroll
    for (int m = 0; m < 4; ++m) { f32x4 z = {0.f,0.f,0.f,0.f}; acc[m][0] = z; acc[m][1] = z; }
#pragma unroll
    for (int k0 = 0; k0 < 4; ++k0) {
      bf16x8 b0 = *(const bf16x8*)(W3b + ((w * 32 + lr)      << 7) + k0 * 32 + lg * 8);
      bf16x8 b1 = *(const bf16x8*)(W3b + ((w * 32 + 16 + lr) << 7) + k0 * 32 + lg * 8);
#pragma unroll
      for (int m = 0; m < 4; ++m) {
        int row = m * 16 + lr;
        bf16x8 a = *(const bf16x8*)(&Ms[msoff_slot(row, k0 * 4 + lg)]);
        acc[m][0] = __builtin_amdgcn_mfma_f32_16x16x32_bf16(a, b0, acc[m][0], 0, 0, 0);
        acc[m][1] = __builtin_amdgcn_mfma_f32_16x16x32_bf16(a, b1, acc[m][1], 0, 0, 0);
      }
    }
    float pr[4][4];
#pragma unroll
    for (int m = 0; m < 4; ++m)
#pragma unroll
      for (int r = 0; r < 4; ++r) pr[m][r] = 0.f;
#pragma unroll
    for (int n = 0; n < 2; ++n) {
      int o = w * 32 + n * 16 + lr;
      float b3 = bc1[o], wc = Wc2[o];
#pragma unroll
      for (int m = 0; m < 4; ++m)
#pragma unroll
        for (int r = 0; r < 4; ++r)
          pr[m][r] += silu_f(acc[m][n][r] + b3) * wc;
    }
#pragma unroll
    for (int m = 0; m < 4; ++m)
#pragma unroll
      for (int r = 0; r < 4; ++r) {
        float v = pr[m][r];
        v += __shfl_xor(v, 1); v += __shfl_xor(v, 2);
        v += __shfl_xor(v, 4); v += __shfl_xor(v, 8);
        pr[m][r] = v;
      }
    if (lr == 0) {
#pragma unroll
      for (int m = 0; m < 4; ++m)
#pragma unroll
        for (int r = 0; r < 4; ++r)
          swred[w][m * 16 + lg * 4 + r] = pr[m][r];
    }
  }
  __syncthreads();

  // ---- segmented aggregation (edges dst-sorted): few atomics per block ----
  const int nv = min(64, E - tbase);
  {
    int c = tid & 127, hf = tid >> 7;
    int e0 = hf * 32;
    int nvh = min(32, nv - e0);
    if (nvh > 0) {
      float run = 0.f;
      int prev = sdst[e0];
#pragma unroll 4
      for (int j = 0; j < nvh; ++j) {
        int e = e0 + j;
        int d = sdst[e];
        float v = bf2f(Ms[msoff(e, c)]);
        if (d != prev) {
          atomicAdd(&aggH[(size_t)prev * 128 + c], run);
          run = 0.f; prev = d;
        }
        run += v;
      }
      atomicAdd(&aggH[(size_t)prev * 128 + c], run);
    }
  }
  if (tid < 6) {
    int c3 = tid % 3, hf = tid / 3;
    int e0 = hf * 32;
    int nvh = min(32, nv - e0);
    if (nvh > 0) {
      float run = 0.f;
      int prev = sdst[e0];
#pragma unroll 4
      for (int j = 0; j < nvh; ++j) {
        int e = e0 + j;
        int d = sdst[e];
        float cwv = swred[0][e] + swred[1][e] + swred[2][e] + swred[3][e];
        if (d != prev) {
          atomicAdd(&coordX[(size_t)prev * 3 + c3], run);
          run = 0.f; prev = d;
        }
        run += sdif[e][c3] * cwv;
      }
      atomicAdd(&coordX[(size_t)prev * 3 + c3], run);
    }
  }
}

// ---- fused node kernel: 64 nodes/block; [h|agg/deg] GEMM -> GEMM -> +h -> LN; x_out ----
__global__ __launch_bounds__(256) void node_kernel(
    const float* __restrict__ h, const float* __restrict__ x,
    const float* __restrict__ bn1, const float* __restrict__ bn2,
    const float* __restrict__ gamma, const float* __restrict__ beta,
    const unsigned short* __restrict__ N1b, const unsigned short* __restrict__ N2b,
    float* __restrict__ aggH, float* __restrict__ coordX,
    const int* __restrict__ deg, int N) {
  __shared__ __align__(16) unsigned short In[64][264];   // [h|agg], reused as f32 hp[64][132]
  __shared__ __align__(16) unsigned short U[64][136];
  __shared__ float scnt[64];

  const int tid  = threadIdx.x;
  const int base = blockIdx.x * 64;
  const int w    = tid >> 6;
  const int lane = tid & 63;
  const int lg   = lane >> 4, lr = lane & 15;
  const int w16  = w * 16;

  if (tid < 64) {
    int n = base + tid;
    scnt[tid] = (n < N) ? fmaxf((float)deg[n], 1.0f) : 1.0f;
  }
  __syncthreads();

#pragma unroll
  for (int it = 0; it < 8; ++it) {
    int idx = tid + it * 256;
    int i = idx >> 5, seg = idx & 31;
    int n = base + i; if (n >= N) n = N - 1;
    float sc = 1.0f;
    const float* p;
    if (seg < 16) { p = h + (size_t)n * 128 + seg * 8; }
    else          { p = aggH + (size_t)n * 128 + (seg - 16) * 8; sc = 1.0f / scnt[i]; }
    float4 a = *(const float4*)p;
    float4 b = *(const float4*)(p + 4);
    uint32_t u0 = cvtpk2(a.x * sc, a.y * sc);
    uint32_t u1 = cvtpk2(a.z * sc, a.w * sc);
    uint32_t u2 = cvtpk2(b.x * sc, b.y * sc);
    uint32_t u3 = cvtpk2(b.z * sc, b.w * sc);
    uint4 v = {u0, u1, u2, u3};
    *(uint4*)&In[i][seg * 8] = v;
  }
  __syncthreads();

  // GEMM n1: [h|agg] @ Wn1^T (+bn1), silu -> U
  {
    f32x4 acc[8];
#pragma unroll
    for (int n = 0; n < 8; ++n) { f32x4 z = {0.f,0.f,0.f,0.f}; acc[n] = z; }
#pragma unroll
    for (int k0 = 0; k0 < 8; ++k0) {
      bf16x8 a = *(const bf16x8*)(&In[w16 + lr][k0 * 32 + lg * 8]);
#pragma unroll
      for (int n = 0; n < 8; ++n) {
        bf16x8 b = *(const bf16x8*)(N1b + ((n * 16 + lr) << 8) + k0 * 32 + lg * 8);
        acc[n] = __builtin_amdgcn_mfma_f32_16x16x32_bf16(a, b, acc[n], 0, 0, 0);
      }
    }
#pragma unroll
    for (int n = 0; n < 8; ++n) {
      int o = n * 16 + lr;
      float b1 = bn1[o];
#pragma unroll
      for (int r = 0; r < 4; ++r) {
        int me = lg * 4 + r;
        U[w16 + me][o] = f2bf(silu_f(acc[n][r] + b1));
      }
    }
  }

  // GEMM n2: U @ Wn2^T (+bn2 +h) -> hp (f32, In arena) [wave-local rows]
  float* hp = (float*)&In[0][0];   // stride 132 f32
  {
    f32x4 acc[8];
#pragma unroll
    for (int n = 0; n < 8; ++n) { f32x4 z = {0.f,0.f,0.f,0.f}; acc[n] = z; }
#pragma unroll
    for (int k0 = 0; k0 < 4; ++k0) {
      bf16x8 a = *(const bf16x8*)(&U[w16 + lr][k0 * 32 + lg * 8]);
#pragma unroll
      for (int n = 0; n < 8; ++n) {
        bf16x8 b = *(const bf16x8*)(N2b + ((n * 16 + lr) << 7) + k0 * 32 + lg * 8);
        acc[n] = __builtin_amdgcn_mfma_f32_16x16x32_bf16(a, b, acc[n], 0, 0, 0);
      }
    }
#pragma unroll
    for (int n = 0; n < 8; ++n) {
      int o = n * 16 + lr;
      float b2 = bn2[o];
#pragma unroll
      for (int r = 0; r < 4; ++r) {
        int me = w16 + lg * 4 + r;
        int ng = base + me; if (ng >= N) ng = N - 1;
        hp[(size_t)me * 132 + o] = acc[n][r] + b2 + h[(size_t)ng * 128 + o];
      }
    }
  }
  __syncthreads();

  // LayerNorm: 4 threads per row
  {
    int r = tid >> 2, q = tid & 3;
    int ng = base + r;
    float s = 0.f, s2 = 0.f;
#pragma unroll
    for (int j = 0; j < 32; ++j) {
      float v = hp[(size_t)r * 132 + q * 32 + j];
      s += v; s2 += v * v;
    }
    s  += __shfl_xor(s, 1);  s  += __shfl_xor(s, 2);
    s2 += __shfl_xor(s2, 1); s2 += __shfl_xor(s2, 2);
    float mu  = s * (1.0f / 128.0f);
    float var = s2 * (1.0f / 128.0f) - mu * mu;
    float rs  = rsqrtf(var + 1e-5f);
    if (ng < N) {
#pragma unroll
      for (int j = 0; j < 32; ++j) {
        int o = q * 32 + j;
        float v = (hp[(size_t)r * 132 + o] - mu) * rs * gamma[o] + beta[o];
        aggH[(size_t)ng * 128 + o] = v;
      }
    }
  }

  // x_out = x + coord_agg / cnt
  if (tid < 192) {
    int i = tid / 3, c = tid % 3;
    int n2 = base + i;
    if (n2 < N) {
      size_t off = (size_t)n2 * 3 + c;
      coordX[off] = x[off] + coordX[off] / scnt[i];
    }
  }
}

extern "C" void kernel_launch(void* const* d_in, const int* in_sizes, int n_in,
                              void* d_out, int out_size, void* d_ws, size_t ws_size,
                              hipStream_t stream) {
  const float* h    = (const float*)d_in[0];
  const float* x    = (const float*)d_in[1];
  const int*   ei   = (const int*)d_in[2];
  const float* We1  = (const float*)d_in[3];
  const float* be1  = (const float*)d_in[4];
  const float* We2  = (const float*)d_in[5];
  const float* be2  = (const float*)d_in[6];
  const float* Wn1  = (const float*)d_in[7];
  const float* bn1  = (const float*)d_in[8];
  const float* Wn2  = (const float*)d_in[9];
  const float* bn2  = (const float*)d_in[10];
  const float* Wc1  = (const float*)d_in[11];
  const float* bc1  = (const float*)d_in[12];
  const float* Wc2  = (const float*)d_in[13];
  const float* gamma = (const float*)d_in[14];
  const float* beta  = (const float*)d_in[15];

  int N = in_sizes[0] / 128;
  int E = in_sizes[2] / 2;

  float* aggH   = (float*)d_out;                       // N*128: agg accumulator -> h_out
  float* coordX = (float*)d_out + (size_t)N * 128;     // N*3:   coord accumulator -> x_out

  char* ws = (char*)d_ws;
  size_t off = 0;
  auto alloc = [&](size_t bytes) {
    char* p = ws + off;
    off = (off + bytes + 255) & ~(size_t)255;
    return p;
  };
  unsigned short* h_bf   = (unsigned short*)alloc((size_t)N * 128 * 2);
  unsigned short* W1b    = (unsigned short*)alloc(128 * 256 * 2);
  unsigned short* W2b    = (unsigned short*)alloc(128 * 128 * 2);
  unsigned short* N1b    = (unsigned short*)alloc(128 * 256 * 2);
  unsigned short* N2b    = (unsigned short*)alloc(128 * 128 * 2);
  unsigned short* W3b    = (unsigned short*)alloc(128 * 128 * 2);
  int*            flag   = (int*)alloc(4);
  int*            deg    = (int*)alloc((size_t)N * 4);
  int*            offs   = (int*)alloc(((size_t)N + 1) * 4);
  int*            cursor = (int*)alloc((size_t)N * 4);
  int*            bsum   = (int*)alloc(256 * 4);
  int*            csr_e  = (int*)alloc((size_t)E * 4);
  (void)ws_size;

  int total = N * 128;
  int nb = (N + 255) / 256;   // N=50000 -> 196 (<=256 required by scanB)

  hipMemsetAsync(d_out, 0, (size_t)out_size * 4, stream);
  hipMemsetAsync(deg, 0, (size_t)N * 4, stream);

  prep_kernel<<<(total + 255) / 256, 256, 0, stream>>>(h, We1, We2, Wn1, Wn2, Wc1, ei,
                                                       h_bf, W1b, W2b, N1b, N2b, W3b, flag,
                                                       total);
  hist_kernel<<<(E + 255) / 256, 256, 0, stream>>>(ei, flag, deg, E);
  scanA_kernel<<<nb, 256, 0, stream>>>(deg, offs, bsum, N);
  scanB_kernel<<<1, 256, 0, stream>>>(bsum, offs, nb, N);
  scanC_kernel<<<nb, 256, 0, stream>>>(bsum, offs, cursor, N);
  scatter_kernel<<<(E + 255) / 256, 256, 0, stream>>>(ei, flag, cursor, csr_e, E);
  edge_kernel<<<(E + 63) / 64, 256, 0, stream>>>(h_bf, x, ei, We1, be1, be2, bc1, Wc2,
                                                 W1b, W2b, W3b, aggH, coordX, csr_e,
                                                 flag, E);
  node_kernel<<<(N + 63) / 64, 256, 0, stream>>>(h, x, bn1, bn2, gamma, beta, N1b, N2b,
                                                 aggH, coordX, deg, N);
}

// Round 5
// 405.599 us; speedup vs baseline: 2.8536x; 1.4892x over previous
//
#include <hip/hip_runtime.h>
#include <stdint.h>

using bf16x8 = __attribute__((ext_vector_type(8))) short;
using f32x4  = __attribute__((ext_vector_type(4))) float;

__device__ __forceinline__ unsigned short f2bf(float f) {
  uint32_t x = __float_as_uint(f);
  x += 0x7fffu + ((x >> 16) & 1u);
  return (unsigned short)(x >> 16);
}
__device__ __forceinline__ float bf2f(unsigned short u) {
  return __uint_as_float(((uint32_t)u) << 16);
}
__device__ __forceinline__ uint32_t cvtpk2(float lo, float hi) {
  uint32_t r;
  asm("v_cvt_pk_bf16_f32 %0, %1, %2" : "=v"(r) : "v"(lo), "v"(hi));
  return r;
}
__device__ __forceinline__ float silu_f(float v) {
  float e = __expf(-v);
  return v * __builtin_amdgcn_rcpf(1.0f + e);
}
__device__ __forceinline__ void unpack2(uint32_t u, float& lo, float& hi) {
  lo = __uint_as_float(u << 16);
  hi = __uint_as_float(u & 0xffff0000u);
}

// Ms rotated-swizzle addressing: row stride 136 ushort (272B, b128-aligned).
__device__ __forceinline__ int msoff(int row, int col) {
  return row * 136 + ((((col >> 3) + row * 4) & 15) << 3) + (col & 7);
}
__device__ __forceinline__ int msoff_slot(int row, int slot) {
  return row * 136 + (((slot + row * 4) & 15) << 3);
}

// ---- prep: weights -> bf16, W1p split layout, w1c column, flag sniff ----
__global__ void prep_kernel(const float* __restrict__ We1, const float* __restrict__ We2,
                            const float* __restrict__ Wn1, const float* __restrict__ Wn2,
                            const float* __restrict__ Wc1, const int* __restrict__ ei,
                            unsigned short* __restrict__ W1p, unsigned short* __restrict__ W2b,
                            unsigned short* __restrict__ N1b, unsigned short* __restrict__ N2b,
                            unsigned short* __restrict__ W3b, float* __restrict__ w1c,
                            int* __restrict__ flag) {
  int i = blockIdx.x * 256 + threadIdx.x;      // 0..32767
  if (i < 256 * 128) {
    // W1p[c][k]: c<128 -> Ws row c (We1[c][0:128]); c>=128 -> Wd row c-128 (We1[c-128][128:256])
    int c = i >> 7, k = i & 127;
    W1p[i] = f2bf(We1[(size_t)(c & 127) * 257 + ((c >> 7) << 7) + k]);
    N1b[i] = f2bf(Wn1[i]);
  }
  if (i < 128 * 128) {
    W2b[i] = f2bf(We2[i]);
    W3b[i] = f2bf(Wc1[i]);
    N2b[i] = f2bf(Wn2[i]);
  }
  if (i < 128) w1c[i] = We1[i * 257 + 256];
  if (i == 0) {
    int allz = 1;
    for (int k = 0; k < 64; ++k) allz &= (ei[2 * k + 1] == 0);
    *flag = allz;   // 1 => int64 indices
  }
}

// ---- CSR-order build: hist + 3-kernel parallel scan + scatter ----
__global__ void hist_kernel(const int* __restrict__ ei, const int* __restrict__ flag,
                            int* __restrict__ deg, int E) {
  int e = blockIdx.x * 256 + threadIdx.x;
  if (e >= E) return;
  int d = (*flag) ? (int)((const long long*)ei)[(size_t)E + e] : ei[E + e];
  atomicAdd(&deg[d], 1);
}

__global__ void scanA_kernel(const int* __restrict__ deg, int* __restrict__ offs,
                             int* __restrict__ bsum, int N) {
  __shared__ int sh[256];
  int t = threadIdx.x, idx = blockIdx.x * 256 + t;
  int v = (idx < N) ? deg[idx] : 0;
  sh[t] = v;
  __syncthreads();
#pragma unroll
  for (int d = 1; d < 256; d <<= 1) {
    int u = (t >= d) ? sh[t - d] : 0;
    __syncthreads();
    sh[t] += u;
    __syncthreads();
  }
  if (idx < N) offs[idx] = sh[t] - v;
  if (t == 255) bsum[blockIdx.x] = sh[255];
}

__global__ void scanB_kernel(int* __restrict__ bsum, int* __restrict__ offs,
                             int nb, int N) {
  __shared__ int sh[256];
  int t = threadIdx.x;
  int v = (t < nb) ? bsum[t] : 0;
  sh[t] = v;
  __syncthreads();
#pragma unroll
  for (int d = 1; d < 256; d <<= 1) {
    int u = (t >= d) ? sh[t - d] : 0;
    __syncthreads();
    sh[t] += u;
    __syncthreads();
  }
  bsum[t] = sh[t] - v;
  if (t == 255) offs[N] = sh[255];
}

__global__ void scanC_kernel(const int* __restrict__ bsum, int* __restrict__ offs,
                             int* __restrict__ cursor, int N) {
  int idx = blockIdx.x * 256 + threadIdx.x;
  if (idx < N) {
    int o = offs[idx] + bsum[blockIdx.x];
    offs[idx] = o;
    cursor[idx] = o;
  }
}

__global__ void scatter_kernel(const int* __restrict__ ei, const int* __restrict__ flag,
                               int* __restrict__ cursor, int* __restrict__ csr_e, int E) {
  int e = blockIdx.x * 256 + threadIdx.x;
  if (e >= E) return;
  int d = (*flag) ? (int)((const long long*)ei)[(size_t)E + e] : ei[E + e];
  int pos = atomicAdd(&cursor[d], 1);
  csr_e[pos] = e;
}

// ---- proj: PsPd[n] = [ h[n]@Ws^T + be1 | h[n]@Wd^T ]  (bf16, 256/node) ----
__global__ __launch_bounds__(256) void proj_kernel(
    const float* __restrict__ h, const float* __restrict__ be1,
    const unsigned short* __restrict__ W1p, unsigned short* __restrict__ PsPd, int N) {
  const int tid = threadIdx.x;
  const int base = blockIdx.x * 64;
  const int w = tid >> 6, lane = tid & 63, lg = lane >> 4, lr = lane & 15;

  f32x4 acc[4][4];
#pragma unroll
  for (int m = 0; m < 4; ++m)
#pragma unroll
    for (int n = 0; n < 4; ++n) { f32x4 z = {0.f,0.f,0.f,0.f}; acc[m][n] = z; }

#pragma unroll
  for (int k0 = 0; k0 < 4; ++k0) {
    bf16x8 b[4];
#pragma unroll
    for (int n = 0; n < 4; ++n)
      b[n] = *(const bf16x8*)(W1p + ((w * 64 + n * 16 + lr) << 7) + k0 * 32 + lg * 8);
#pragma unroll
    for (int m = 0; m < 4; ++m) {
      int row = base + m * 16 + lr; if (row >= N) row = N - 1;
      const float* p = h + (size_t)row * 128 + k0 * 32 + lg * 8;
      float4 fa = *(const float4*)p;
      float4 fb = *(const float4*)(p + 4);
      uint32_t u0 = cvtpk2(fa.x, fa.y), u1 = cvtpk2(fa.z, fa.w);
      uint32_t u2 = cvtpk2(fb.x, fb.y), u3 = cvtpk2(fb.z, fb.w);
      union { uint32_t u[4]; bf16x8 v; } cv;
      cv.u[0] = u0; cv.u[1] = u1; cv.u[2] = u2; cv.u[3] = u3;
#pragma unroll
      for (int n = 0; n < 4; ++n)
        acc[m][n] = __builtin_amdgcn_mfma_f32_16x16x32_bf16(cv.v, b[n], acc[m][n], 0, 0, 0);
    }
  }
#pragma unroll
  for (int n = 0; n < 4; ++n) {
    int o = w * 64 + n * 16 + lr;
    float add = (o < 128) ? be1[o] : 0.f;    // fold be1 into Ps half
#pragma unroll
    for (int m = 0; m < 4; ++m)
#pragma unroll
      for (int r = 0; r < 4; ++r) {
        int row = base + m * 16 + lg * 4 + r;
        if (row < N) PsPd[(size_t)row * 256 + o] = f2bf(acc[m][n][r] + add);
      }
  }
}

// ---- fused edge kernel: 64 dst-sorted edges/block; gather Ps/Pd + combine,
//      GEMM2, GEMM3, segmented aggregation ----
__global__ __launch_bounds__(256, 4) void edge_kernel(
    const unsigned short* __restrict__ PsPd, const float* __restrict__ x,
    const int* __restrict__ ei, const float* __restrict__ w1c,
    const float* __restrict__ be2, const float* __restrict__ bc1,
    const float* __restrict__ Wc2,
    const unsigned short* __restrict__ W2b, const unsigned short* __restrict__ W3b,
    float* __restrict__ aggH, float* __restrict__ coordX,
    const int* __restrict__ csr_e, const int* __restrict__ flag, int E) {
  __shared__ __align__(16) unsigned short Ms[64 * 136];  // combine out, then Ms2
  __shared__ float swred[4][64];
  __shared__ int   ssrc[64], sdst[64];
  __shared__ float sds[64];
  __shared__ float sdif[64][3];

  const int tid   = threadIdx.x;
  const int tbase = blockIdx.x * 64;
  const int w = tid >> 6, lane = tid & 63, lg = lane >> 4, lr = lane & 15;

  // phase 0: indices + geometry (dst-sorted via csr_e)
  if (tid < 64) {
    int pos = tbase + tid;
    int s = 0, d = 0;
    if (pos < E) {
      int eid = csr_e[pos];
      if (*flag) {
        s = (int)((const long long*)ei)[eid];
        d = (int)((const long long*)ei)[(size_t)E + eid];
      } else {
        s = ei[eid];
        d = ei[E + eid];
      }
    }
    ssrc[tid] = s; sdst[tid] = d;
    float dx = x[s * 3 + 0] - x[d * 3 + 0];
    float dy = x[s * 3 + 1] - x[d * 3 + 1];
    float dz = x[s * 3 + 2] - x[d * 3 + 2];
    sdif[tid][0] = dx; sdif[tid][1] = dy; sdif[tid][2] = dz;
    sds[tid] = dx * dx + dy * dy + dz * dz;
  }
  __syncthreads();

  // ---- gather Ps[src]/Pd[dst] (issue all 8 loads), combine + silu -> Ms ----
  {
    uint4 av[4], bv[4];
#pragma unroll
    for (int it = 0; it < 4; ++it) {
      int idx = tid + it * 256;            // 0..1023
      int e = idx >> 4, seg = idx & 15;
      av[it] = *(const uint4*)(PsPd + (size_t)ssrc[e] * 256 + seg * 8);
      bv[it] = *(const uint4*)(PsPd + (size_t)sdst[e] * 256 + 128 + seg * 8);
    }
    const float4* w4 = (const float4*)w1c;
#pragma unroll
    for (int it = 0; it < 4; ++it) {
      int idx = tid + it * 256;
      int e = idx >> 4, seg = idx & 15;
      float dsv = sds[e];
      float4 wA = w4[seg * 2], wB = w4[seg * 2 + 1];
      float a0,a1,a2,a3,a4,a5,a6,a7, b0,b1,b2,b3,b4,b5,b6,b7;
      unpack2(((uint32_t*)&av[it])[0], a0, a1);
      unpack2(((uint32_t*)&av[it])[1], a2, a3);
      unpack2(((uint32_t*)&av[it])[2], a4, a5);
      unpack2(((uint32_t*)&av[it])[3], a6, a7);
      unpack2(((uint32_t*)&bv[it])[0], b0, b1);
      unpack2(((uint32_t*)&bv[it])[1], b2, b3);
      unpack2(((uint32_t*)&bv[it])[2], b4, b5);
      unpack2(((uint32_t*)&bv[it])[3], b6, b7);
      float v0 = silu_f(a0 + b0 + dsv * wA.x);
      float v1 = silu_f(a1 + b1 + dsv * wA.y);
      float v2 = silu_f(a2 + b2 + dsv * wA.z);
      float v3 = silu_f(a3 + b3 + dsv * wA.w);
      float v4 = silu_f(a4 + b4 + dsv * wB.x);
      float v5 = silu_f(a5 + b5 + dsv * wB.y);
      float v6 = silu_f(a6 + b6 + dsv * wB.z);
      float v7 = silu_f(a7 + b7 + dsv * wB.w);
      uint4 o;
      o.x = cvtpk2(v0, v1); o.y = cvtpk2(v2, v3);
      o.z = cvtpk2(v4, v5); o.w = cvtpk2(v6, v7);
      *(uint4*)(&Ms[msoff_slot(e, seg)]) = o;
    }
  }
  __syncthreads();

  // ---- GEMM2: Ms @ We2^T (+be2), silu -> Ms2 (same arena) ----
  {
    f32x4 acc[4][2];
#pragma unroll
    for (int m = 0; m < 4; ++m) { f32x4 z = {0.f,0.f,0.f,0.f}; acc[m][0] = z; acc[m][1] = z; }
#pragma unroll
    for (int k0 = 0; k0 < 4; ++k0) {
      bf16x8 b0 = *(const bf16x8*)(W2b + ((w * 32 + lr)      << 7) + k0 * 32 + lg * 8);
      bf16x8 b1 = *(const bf16x8*)(W2b + ((w * 32 + 16 + lr) << 7) + k0 * 32 + lg * 8);
#pragma unroll
      for (int m = 0; m < 4; ++m) {
        int row = m * 16 + lr;
        bf16x8 a = *(const bf16x8*)(&Ms[msoff_slot(row, k0 * 4 + lg)]);
        acc[m][0] = __builtin_amdgcn_mfma_f32_16x16x32_bf16(a, b0, acc[m][0], 0, 0, 0);
        acc[m][1] = __builtin_amdgcn_mfma_f32_16x16x32_bf16(a, b1, acc[m][1], 0, 0, 0);
      }
    }
    uint32_t pk[4][2][2];
#pragma unroll
    for (int n = 0; n < 2; ++n) {
      int o = w * 32 + n * 16 + lr;
      float b2v = be2[o];
#pragma unroll
      for (int m = 0; m < 4; ++m)
#pragma unroll
        for (int r = 0; r < 4; r += 2)
          pk[m][n][r >> 1] = cvtpk2(silu_f(acc[m][n][r] + b2v),
                                    silu_f(acc[m][n][r + 1] + b2v));
    }
    __syncthreads();   // all waves done READING Ms
#pragma unroll
    for (int n = 0; n < 2; ++n) {
      int o = w * 32 + n * 16 + lr;
#pragma unroll
      for (int m = 0; m < 4; ++m)
#pragma unroll
        for (int r = 0; r < 4; r += 2) {
          int row = m * 16 + lg * 4 + r;
          uint32_t u = pk[m][n][r >> 1];
          Ms[msoff(row, o)]     = (unsigned short)(u & 0xffffu);
          Ms[msoff(row + 1, o)] = (unsigned short)(u >> 16);
        }
    }
  }
  __syncthreads();

  // ---- GEMM3: Ms2 @ Wc1^T, silu, dot Wc2 -> swred ----
  {
    f32x4 acc[4][2];
#pragma unroll
    for (int m = 0; m < 4; ++m) { f32x4 z = {0.f,0.f,0.f,0.f}; acc[m][0] = z; acc[m][1] = z; }
#pragma unroll
    for (int k0 = 0; k0 < 4; ++k0) {
      bf16x8 b0 = *(const bf16x8*)(W3b + ((w * 32 + lr)      << 7) + k0 * 32 + lg * 8);
      bf16x8 b1 = *(const bf16x8*)(W3b + ((w * 32 + 16 + lr) << 7) + k0 * 32 + lg * 8);
#pragma unroll
      for (int m = 0; m < 4; ++m) {
        int row = m * 16 + lr;
        bf16x8 a = *(const bf16x8*)(&Ms[msoff_slot(row, k0 * 4 + lg)]);
        acc[m][0] = __builtin_amdgcn_mfma_f32_16x16x32_bf16(a, b0, acc[m][0], 0, 0, 0);
        acc[m][1] = __builtin_amdgcn_mfma_f32_16x16x32_bf16(a, b1, acc[m][1], 0, 0, 0);
      }
    }
    float pr[4][4];
#pragma unroll
    for (int m = 0; m < 4; ++m)
#pragma unroll
      for (int r = 0; r < 4; ++r) pr[m][r] = 0.f;
#pragma unroll
    for (int n = 0; n < 2; ++n) {
      int o = w * 32 + n * 16 + lr;
      float b3 = bc1[o], wc = Wc2[o];
#pragma unroll
      for (int m = 0; m < 4; ++m)
#pragma unroll
        for (int r = 0; r < 4; ++r)
          pr[m][r] += silu_f(acc[m][n][r] + b3) * wc;
    }
#pragma unroll
    for (int m = 0; m < 4; ++m)
#pragma unroll
      for (int r = 0; r < 4; ++r) {
        float v = pr[m][r];
        v += __shfl_xor(v, 1); v += __shfl_xor(v, 2);
        v += __shfl_xor(v, 4); v += __shfl_xor(v, 8);
        pr[m][r] = v;
      }
    if (lr == 0) {
#pragma unroll
      for (int m = 0; m < 4; ++m)
#pragma unroll
        for (int r = 0; r < 4; ++r)
          swred[w][m * 16 + lg * 4 + r] = pr[m][r];
    }
  }
  __syncthreads();

  // ---- segmented aggregation (dst-sorted): few atomics per block ----
  const int nv = min(64, E - tbase);
  {
    int c = tid & 127, hf = tid >> 7;
    int e0 = hf * 32;
    int nvh = min(32, nv - e0);
    if (nvh > 0) {
      float run = 0.f;
      int prev = sdst[e0];
#pragma unroll 4
      for (int j = 0; j < nvh; ++j) {
        int e = e0 + j;
        int d = sdst[e];
        float v = bf2f(Ms[msoff(e, c)]);
        if (d != prev) {
          atomicAdd(&aggH[(size_t)prev * 128 + c], run);
          run = 0.f; prev = d;
        }
        run += v;
      }
      atomicAdd(&aggH[(size_t)prev * 128 + c], run);
    }
  }
  if (tid < 6) {
    int c3 = tid % 3, hf = tid / 3;
    int e0 = hf * 32;
    int nvh = min(32, nv - e0);
    if (nvh > 0) {
      float run = 0.f;
      int prev = sdst[e0];
#pragma unroll 4
      for (int j = 0; j < nvh; ++j) {
        int e = e0 + j;
        int d = sdst[e];
        float cwv = swred[0][e] + swred[1][e] + swred[2][e] + swred[3][e];
        if (d != prev) {
          atomicAdd(&coordX[(size_t)prev * 3 + c3], run);
          run = 0.f; prev = d;
        }
        run += sdif[e][c3] * cwv;
      }
      atomicAdd(&coordX[(size_t)prev * 3 + c3], run);
    }
  }
}

// ---- fused node kernel: 64 nodes/block; [h|agg/deg] GEMM -> GEMM -> +h -> LN; x_out ----
__global__ __launch_bounds__(256) void node_kernel(
    const float* __restrict__ h, const float* __restrict__ x,
    const float* __restrict__ bn1, const float* __restrict__ bn2,
    const float* __restrict__ gamma, const float* __restrict__ beta,
    const unsigned short* __restrict__ N1b, const unsigned short* __restrict__ N2b,
    float* __restrict__ aggH, float* __restrict__ coordX,
    const int* __restrict__ deg, int N) {
  __shared__ __align__(16) unsigned short In[64][264];
  __shared__ __align__(16) unsigned short U[64][136];
  __shared__ float scnt[64];

  const int tid  = threadIdx.x;
  const int base = blockIdx.x * 64;
  const int w    = tid >> 6;
  const int lane = tid & 63;
  const int lg   = lane >> 4, lr = lane & 15;
  const int w16  = w * 16;

  if (tid < 64) {
    int n = base + tid;
    scnt[tid] = (n < N) ? fmaxf((float)deg[n], 1.0f) : 1.0f;
  }
  __syncthreads();

#pragma unroll
  for (int it = 0; it < 8; ++it) {
    int idx = tid + it * 256;
    int i = idx >> 5, seg = idx & 31;
    int n = base + i; if (n >= N) n = N - 1;
    float sc = 1.0f;
    const float* p;
    if (seg < 16) { p = h + (size_t)n * 128 + seg * 8; }
    else          { p = aggH + (size_t)n * 128 + (seg - 16) * 8; sc = 1.0f / scnt[i]; }
    float4 a = *(const float4*)p;
    float4 b = *(const float4*)(p + 4);
    uint32_t u0 = cvtpk2(a.x * sc, a.y * sc);
    uint32_t u1 = cvtpk2(a.z * sc, a.w * sc);
    uint32_t u2 = cvtpk2(b.x * sc, b.y * sc);
    uint32_t u3 = cvtpk2(b.z * sc, b.w * sc);
    uint4 v = {u0, u1, u2, u3};
    *(uint4*)&In[i][seg * 8] = v;
  }
  __syncthreads();

  {
    f32x4 acc[8];
#pragma unroll
    for (int n = 0; n < 8; ++n) { f32x4 z = {0.f,0.f,0.f,0.f}; acc[n] = z; }
#pragma unroll
    for (int k0 = 0; k0 < 8; ++k0) {
      bf16x8 a = *(const bf16x8*)(&In[w16 + lr][k0 * 32 + lg * 8]);
#pragma unroll
      for (int n = 0; n < 8; ++n) {
        bf16x8 b = *(const bf16x8*)(N1b + ((n * 16 + lr) << 8) + k0 * 32 + lg * 8);
        acc[n] = __builtin_amdgcn_mfma_f32_16x16x32_bf16(a, b, acc[n], 0, 0, 0);
      }
    }
#pragma unroll
    for (int n = 0; n < 8; ++n) {
      int o = n * 16 + lr;
      float b1 = bn1[o];
#pragma unroll
      for (int r = 0; r < 4; ++r) {
        int me = lg * 4 + r;
        U[w16 + me][o] = f2bf(silu_f(acc[n][r] + b1));
      }
    }
  }

  float* hp = (float*)&In[0][0];   // stride 132 f32
  {
    f32x4 acc[8];
#pragma unroll
    for (int n = 0; n < 8; ++n) { f32x4 z = {0.f,0.f,0.f,0.f}; acc[n] = z; }
#pragma unroll
    for (int k0 = 0; k0 < 4; ++k0) {
      bf16x8 a = *(const bf16x8*)(&U[w16 + lr][k0 * 32 + lg * 8]);
#pragma unroll
      for (int n = 0; n < 8; ++n) {
        bf16x8 b = *(const bf16x8*)(N2b + ((n * 16 + lr) << 7) + k0 * 32 + lg * 8);
        acc[n] = __builtin_amdgcn_mfma_f32_16x16x32_bf16(a, b, acc[n], 0, 0, 0);
      }
    }
#pragma unroll
    for (int n = 0; n < 8; ++n) {
      int o = n * 16 + lr;
      float b2 = bn2[o];
#pragma unroll
      for (int r = 0; r < 4; ++r) {
        int me = w16 + lg * 4 + r;
        int ng = base + me; if (ng >= N) ng = N - 1;
        hp[(size_t)me * 132 + o] = acc[n][r] + b2 + h[(size_t)ng * 128 + o];
      }
    }
  }
  __syncthreads();

  {
    int r = tid >> 2, q = tid & 3;
    int ng = base + r;
    float s = 0.f, s2 = 0.f;
#pragma unroll
    for (int j = 0; j < 32; ++j) {
      float v = hp[(size_t)r * 132 + q * 32 + j];
      s += v; s2 += v * v;
    }
    s  += __shfl_xor(s, 1);  s  += __shfl_xor(s, 2);
    s2 += __shfl_xor(s2, 1); s2 += __shfl_xor(s2, 2);
    float mu  = s * (1.0f / 128.0f);
    float var = s2 * (1.0f / 128.0f) - mu * mu;
    float rs  = rsqrtf(var + 1e-5f);
    if (ng < N) {
#pragma unroll
      for (int j = 0; j < 32; ++j) {
        int o = q * 32 + j;
        float v = (hp[(size_t)r * 132 + o] - mu) * rs * gamma[o] + beta[o];
        aggH[(size_t)ng * 128 + o] = v;
      }
    }
  }

  if (tid < 192) {
    int i = tid / 3, c = tid % 3;
    int n2 = base + i;
    if (n2 < N) {
      size_t off = (size_t)n2 * 3 + c;
      coordX[off] = x[off] + coordX[off] / scnt[i];
    }
  }
}

extern "C" void kernel_launch(void* const* d_in, const int* in_sizes, int n_in,
                              void* d_out, int out_size, void* d_ws, size_t ws_size,
                              hipStream_t stream) {
  const float* h    = (const float*)d_in[0];
  const float* x    = (const float*)d_in[1];
  const int*   ei   = (const int*)d_in[2];
  const float* We1  = (const float*)d_in[3];
  const float* be1  = (const float*)d_in[4];
  const float* We2  = (const float*)d_in[5];
  const float* be2  = (const float*)d_in[6];
  const float* Wn1  = (const float*)d_in[7];
  const float* bn1  = (const float*)d_in[8];
  const float* Wn2  = (const float*)d_in[9];
  const float* bn2  = (const float*)d_in[10];
  const float* Wc1  = (const float*)d_in[11];
  const float* bc1  = (const float*)d_in[12];
  const float* Wc2  = (const float*)d_in[13];
  const float* gamma = (const float*)d_in[14];
  const float* beta  = (const float*)d_in[15];

  int N = in_sizes[0] / 128;
  int E = in_sizes[2] / 2;

  float* aggH   = (float*)d_out;                       // N*128: agg accumulator -> h_out
  float* coordX = (float*)d_out + (size_t)N * 128;     // N*3:   coord accumulator -> x_out

  char* ws = (char*)d_ws;
  size_t off = 0;
  auto alloc = [&](size_t bytes) {
    char* p = ws + off;
    off = (off + bytes + 255) & ~(size_t)255;
    return p;
  };
  unsigned short* PsPd   = (unsigned short*)alloc((size_t)N * 256 * 2);
  unsigned short* W1p    = (unsigned short*)alloc(256 * 128 * 2);
  unsigned short* W2b    = (unsigned short*)alloc(128 * 128 * 2);
  unsigned short* N1b    = (unsigned short*)alloc(128 * 256 * 2);
  unsigned short* N2b    = (unsigned short*)alloc(128 * 128 * 2);
  unsigned short* W3b    = (unsigned short*)alloc(128 * 128 * 2);
  float*          w1c    = (float*)alloc(128 * 4);
  int*            flag   = (int*)alloc(4);
  int*            deg    = (int*)alloc((size_t)N * 4);
  int*            offs   = (int*)alloc(((size_t)N + 1) * 4);
  int*            cursor = (int*)alloc((size_t)N * 4);
  int*            bsum   = (int*)alloc(256 * 4);
  int*            csr_e  = (int*)alloc((size_t)E * 4);
  (void)ws_size;

  int nb = (N + 255) / 256;   // N=50000 -> 196 (<=256 required by scanB)

  hipMemsetAsync(d_out, 0, (size_t)out_size * 4, stream);
  hipMemsetAsync(deg, 0, (size_t)N * 4, stream);

  prep_kernel<<<128, 256, 0, stream>>>(We1, We2, Wn1, Wn2, Wc1, ei,
                                       W1p, W2b, N1b, N2b, W3b, w1c, flag);
  hist_kernel<<<(E + 255) / 256, 256, 0, stream>>>(ei, flag, deg, E);
  scanA_kernel<<<nb, 256, 0, stream>>>(deg, offs, bsum, N);
  scanB_kernel<<<1, 256, 0, stream>>>(bsum, offs, nb, N);
  scanC_kernel<<<nb, 256, 0, stream>>>(bsum, offs, cursor, N);
  scatter_kernel<<<(E + 255) / 256, 256, 0, stream>>>(ei, flag, cursor, csr_e, E);
  proj_kernel<<<(N + 63) / 64, 256, 0, stream>>>(h, be1, W1p, PsPd, N);
  edge_kernel<<<(E + 63) / 64, 256, 0, stream>>>(PsPd, x, ei, w1c, be2, bc1, Wc2,
                                                 W2b, W3b, aggH, coordX, csr_e, flag, E);
  node_kernel<<<(N + 63) / 64, 256, 0, stream>>>(h, x, bn1, bn2, gamma, beta, N1b, N2b,
                                                 aggH, coordX, deg, N);
}

// Round 6
// 402.779 us; speedup vs baseline: 2.8735x; 1.0070x over previous
//
#include <hip/hip_runtime.h>
#include <stdint.h>

using bf16x8 = __attribute__((ext_vector_type(8))) short;
using f32x4  = __attribute__((ext_vector_type(4))) float;

__device__ __forceinline__ unsigned short f2bf(float f) {
  uint32_t x = __float_as_uint(f);
  x += 0x7fffu + ((x >> 16) & 1u);
  return (unsigned short)(x >> 16);
}
__device__ __forceinline__ float bf2f(unsigned short u) {
  return __uint_as_float(((uint32_t)u) << 16);
}
__device__ __forceinline__ uint32_t cvtpk2(float lo, float hi) {
  uint32_t r;
  asm("v_cvt_pk_bf16_f32 %0, %1, %2" : "=v"(r) : "v"(lo), "v"(hi));
  return r;
}
__device__ __forceinline__ float silu_f(float v) {
  float e = __expf(-v);
  return v * __builtin_amdgcn_rcpf(1.0f + e);
}
__device__ __forceinline__ void unpack2(uint32_t u, float& lo, float& hi) {
  lo = __uint_as_float(u << 16);
  hi = __uint_as_float(u & 0xffff0000u);
}

// Ms rotated-swizzle addressing: row stride 136 ushort (272B, b128-aligned).
__device__ __forceinline__ int msoff(int row, int col) {
  return row * 136 + ((((col >> 3) + row * 4) & 15) << 3) + (col & 7);
}
__device__ __forceinline__ int msoff_slot(int row, int slot) {
  return row * 136 + (((slot + row * 4) & 15) << 3);
}

// ---- prep: weights -> bf16, W1p split layout, w1c column, flag sniff ----
__global__ void prep_kernel(const float* __restrict__ We1, const float* __restrict__ We2,
                            const float* __restrict__ Wn1, const float* __restrict__ Wn2,
                            const float* __restrict__ Wc1, const int* __restrict__ ei,
                            unsigned short* __restrict__ W1p, unsigned short* __restrict__ W2b,
                            unsigned short* __restrict__ N1b, unsigned short* __restrict__ N2b,
                            unsigned short* __restrict__ W3b, float* __restrict__ w1c,
                            int* __restrict__ flag) {
  int i = blockIdx.x * 256 + threadIdx.x;      // 0..32767
  if (i < 256 * 128) {
    // W1p[c][k]: c<128 -> Ws row c (We1[c][0:128]); c>=128 -> Wd row c-128 (We1[c-128][128:256])
    int c = i >> 7, k = i & 127;
    W1p[i] = f2bf(We1[(size_t)(c & 127) * 257 + ((c >> 7) << 7) + k]);
    N1b[i] = f2bf(Wn1[i]);
  }
  if (i < 128 * 128) {
    W2b[i] = f2bf(We2[i]);
    W3b[i] = f2bf(Wc1[i]);
    N2b[i] = f2bf(Wn2[i]);
  }
  if (i < 128) w1c[i] = We1[i * 257 + 256];
  if (i == 0) {
    int allz = 1;
    for (int k = 0; k < 64; ++k) allz &= (ei[2 * k + 1] == 0);
    *flag = allz;   // 1 => int64 indices
  }
}

// ---- CSR-order build: hist + 3-kernel parallel scan + scatter ----
__global__ void hist_kernel(const int* __restrict__ ei, const int* __restrict__ flag,
                            int* __restrict__ deg, int E) {
  int e = blockIdx.x * 256 + threadIdx.x;
  if (e >= E) return;
  int d = (*flag) ? (int)((const long long*)ei)[(size_t)E + e] : ei[E + e];
  atomicAdd(&deg[d], 1);
}

__global__ void scanA_kernel(const int* __restrict__ deg, int* __restrict__ offs,
                             int* __restrict__ bsum, int N) {
  __shared__ int sh[256];
  int t = threadIdx.x, idx = blockIdx.x * 256 + t;
  int v = (idx < N) ? deg[idx] : 0;
  sh[t] = v;
  __syncthreads();
#pragma unroll
  for (int d = 1; d < 256; d <<= 1) {
    int u = (t >= d) ? sh[t - d] : 0;
    __syncthreads();
    sh[t] += u;
    __syncthreads();
  }
  if (idx < N) offs[idx] = sh[t] - v;
  if (t == 255) bsum[blockIdx.x] = sh[255];
}

__global__ void scanB_kernel(int* __restrict__ bsum, int* __restrict__ offs,
                             int nb, int N) {
  __shared__ int sh[256];
  int t = threadIdx.x;
  int v = (t < nb) ? bsum[t] : 0;
  sh[t] = v;
  __syncthreads();
#pragma unroll
  for (int d = 1; d < 256; d <<= 1) {
    int u = (t >= d) ? sh[t - d] : 0;
    __syncthreads();
    sh[t] += u;
    __syncthreads();
  }
  bsum[t] = sh[t] - v;
  if (t == 255) offs[N] = sh[255];
}

__global__ void scanC_kernel(const int* __restrict__ bsum, int* __restrict__ offs,
                             int* __restrict__ cursor, int N) {
  int idx = blockIdx.x * 256 + threadIdx.x;
  if (idx < N) {
    int o = offs[idx] + bsum[blockIdx.x];
    offs[idx] = o;
    cursor[idx] = o;
  }
}

__global__ void scatter_kernel(const int* __restrict__ ei, const int* __restrict__ flag,
                               int* __restrict__ cursor, int* __restrict__ csr_e, int E) {
  int e = blockIdx.x * 256 + threadIdx.x;
  if (e >= E) return;
  int d = (*flag) ? (int)((const long long*)ei)[(size_t)E + e] : ei[E + e];
  int pos = atomicAdd(&cursor[d], 1);
  csr_e[pos] = e;
}

// ---- proj: PsPd[n] = [ h[n]@Ws^T + be1 | h[n]@Wd^T ]  (bf16, 256/node) ----
__global__ __launch_bounds__(256) void proj_kernel(
    const float* __restrict__ h, const float* __restrict__ be1,
    const unsigned short* __restrict__ W1p, unsigned short* __restrict__ PsPd, int N) {
  const int tid = threadIdx.x;
  const int base = blockIdx.x * 64;
  const int w = tid >> 6, lane = tid & 63, lg = lane >> 4, lr = lane & 15;

  f32x4 acc[4][4];
#pragma unroll
  for (int m = 0; m < 4; ++m)
#pragma unroll
    for (int n = 0; n < 4; ++n) { f32x4 z = {0.f,0.f,0.f,0.f}; acc[m][n] = z; }

#pragma unroll
  for (int k0 = 0; k0 < 4; ++k0) {
    bf16x8 b[4];
#pragma unroll
    for (int n = 0; n < 4; ++n)
      b[n] = *(const bf16x8*)(W1p + ((w * 64 + n * 16 + lr) << 7) + k0 * 32 + lg * 8);
#pragma unroll
    for (int m = 0; m < 4; ++m) {
      int row = base + m * 16 + lr; if (row >= N) row = N - 1;
      const float* p = h + (size_t)row * 128 + k0 * 32 + lg * 8;
      float4 fa = *(const float4*)p;
      float4 fb = *(const float4*)(p + 4);
      uint32_t u0 = cvtpk2(fa.x, fa.y), u1 = cvtpk2(fa.z, fa.w);
      uint32_t u2 = cvtpk2(fb.x, fb.y), u3 = cvtpk2(fb.z, fb.w);
      union { uint32_t u[4]; bf16x8 v; } cv;
      cv.u[0] = u0; cv.u[1] = u1; cv.u[2] = u2; cv.u[3] = u3;
#pragma unroll
      for (int n = 0; n < 4; ++n)
        acc[m][n] = __builtin_amdgcn_mfma_f32_16x16x32_bf16(cv.v, b[n], acc[m][n], 0, 0, 0);
    }
  }
#pragma unroll
  for (int n = 0; n < 4; ++n) {
    int o = w * 64 + n * 16 + lr;
    float add = (o < 128) ? be1[o] : 0.f;    // fold be1 into Ps half
#pragma unroll
    for (int m = 0; m < 4; ++m)
#pragma unroll
      for (int r = 0; r < 4; ++r) {
        int row = base + m * 16 + lg * 4 + r;
        if (row < N) PsPd[(size_t)row * 256 + o] = f2bf(acc[m][n][r] + add);
      }
  }
}

// ---- fused edge kernel: 64 dst-sorted edges/block; gather Ps/Pd + combine,
//      GEMM2, GEMM3, segmented aggregation ----
__global__ __launch_bounds__(256, 4) void edge_kernel(
    const unsigned short* __restrict__ PsPd, const float* __restrict__ x,
    const int* __restrict__ ei, const float* __restrict__ w1c,
    const float* __restrict__ be2, const float* __restrict__ bc1,
    const float* __restrict__ Wc2,
    const unsigned short* __restrict__ W2b, const unsigned short* __restrict__ W3b,
    float* __restrict__ aggH, float* __restrict__ coordX,
    const int* __restrict__ csr_e, const int* __restrict__ flag, int E) {
  __shared__ __align__(16) unsigned short Ms[64 * 136];  // combine out, then Ms2
  __shared__ float swred[4][64];
  __shared__ int   ssrc[64], sdst[64];
  __shared__ float sds[64];
  __shared__ float sdif[64][3];

  const int tid   = threadIdx.x;
  const int tbase = blockIdx.x * 64;
  const int w = tid >> 6, lane = tid & 63, lg = lane >> 4, lr = lane & 15;

  // phase 0: indices + geometry (dst-sorted via csr_e)
  if (tid < 64) {
    int pos = tbase + tid;
    int s = 0, d = 0;
    if (pos < E) {
      int eid = csr_e[pos];
      if (*flag) {
        s = (int)((const long long*)ei)[eid];
        d = (int)((const long long*)ei)[(size_t)E + eid];
      } else {
        s = ei[eid];
        d = ei[E + eid];
      }
    }
    ssrc[tid] = s; sdst[tid] = d;
    float dx = x[s * 3 + 0] - x[d * 3 + 0];
    float dy = x[s * 3 + 1] - x[d * 3 + 1];
    float dz = x[s * 3 + 2] - x[d * 3 + 2];
    sdif[tid][0] = dx; sdif[tid][1] = dy; sdif[tid][2] = dz;
    sds[tid] = dx * dx + dy * dy + dz * dz;
  }
  __syncthreads();

  // ---- gather Ps[src]/Pd[dst] (issue all 8 loads), combine + silu -> Ms ----
  {
    uint4 av[4], bv[4];
#pragma unroll
    for (int it = 0; it < 4; ++it) {
      int idx = tid + it * 256;            // 0..1023
      int e = idx >> 4, seg = idx & 15;
      av[it] = *(const uint4*)(PsPd + (size_t)ssrc[e] * 256 + seg * 8);
      bv[it] = *(const uint4*)(PsPd + (size_t)sdst[e] * 256 + 128 + seg * 8);
    }
    const float4* w4 = (const float4*)w1c;
#pragma unroll
    for (int it = 0; it < 4; ++it) {
      int idx = tid + it * 256;
      int e = idx >> 4, seg = idx & 15;
      float dsv = sds[e];
      float4 wA = w4[seg * 2], wB = w4[seg * 2 + 1];
      float a0,a1,a2,a3,a4,a5,a6,a7, b0,b1,b2,b3,b4,b5,b6,b7;
      unpack2(((uint32_t*)&av[it])[0], a0, a1);
      unpack2(((uint32_t*)&av[it])[1], a2, a3);
      unpack2(((uint32_t*)&av[it])[2], a4, a5);
      unpack2(((uint32_t*)&av[it])[3], a6, a7);
      unpack2(((uint32_t*)&bv[it])[0], b0, b1);
      unpack2(((uint32_t*)&bv[it])[1], b2, b3);
      unpack2(((uint32_t*)&bv[it])[2], b4, b5);
      unpack2(((uint32_t*)&bv[it])[3], b6, b7);
      float v0 = silu_f(a0 + b0 + dsv * wA.x);
      float v1 = silu_f(a1 + b1 + dsv * wA.y);
      float v2 = silu_f(a2 + b2 + dsv * wA.z);
      float v3 = silu_f(a3 + b3 + dsv * wA.w);
      float v4 = silu_f(a4 + b4 + dsv * wB.x);
      float v5 = silu_f(a5 + b5 + dsv * wB.y);
      float v6 = silu_f(a6 + b6 + dsv * wB.z);
      float v7 = silu_f(a7 + b7 + dsv * wB.w);
      uint4 o;
      o.x = cvtpk2(v0, v1); o.y = cvtpk2(v2, v3);
      o.z = cvtpk2(v4, v5); o.w = cvtpk2(v6, v7);
      *(uint4*)(&Ms[msoff_slot(e, seg)]) = o;
    }
  }
  __syncthreads();

  // ---- GEMM2: Ms @ We2^T (+be2), silu -> Ms2 (same arena) ----
  {
    f32x4 acc[4][2];
#pragma unroll
    for (int m = 0; m < 4; ++m) { f32x4 z = {0.f,0.f,0.f,0.f}; acc[m][0] = z; acc[m][1] = z; }
#pragma unroll
    for (int k0 = 0; k0 < 4; ++k0) {
      bf16x8 b0 = *(const bf16x8*)(W2b + ((w * 32 + lr)      << 7) + k0 * 32 + lg * 8);
      bf16x8 b1 = *(const bf16x8*)(W2b + ((w * 32 + 16 + lr) << 7) + k0 * 32 + lg * 8);
#pragma unroll
      for (int m = 0; m < 4; ++m) {
        int row = m * 16 + lr;
        bf16x8 a = *(const bf16x8*)(&Ms[msoff_slot(row, k0 * 4 + lg)]);
        acc[m][0] = __builtin_amdgcn_mfma_f32_16x16x32_bf16(a, b0, acc[m][0], 0, 0, 0);
        acc[m][1] = __builtin_amdgcn_mfma_f32_16x16x32_bf16(a, b1, acc[m][1], 0, 0, 0);
      }
    }
    uint32_t pk[4][2][2];
#pragma unroll
    for (int n = 0; n < 2; ++n) {
      int o = w * 32 + n * 16 + lr;
      float b2v = be2[o];
#pragma unroll
      for (int m = 0; m < 4; ++m)
#pragma unroll
        for (int r = 0; r < 4; r += 2)
          pk[m][n][r >> 1] = cvtpk2(silu_f(acc[m][n][r] + b2v),
                                    silu_f(acc[m][n][r + 1] + b2v));
    }
    __syncthreads();   // all waves done READING Ms
#pragma unroll
    for (int n = 0; n < 2; ++n) {
      int o = w * 32 + n * 16 + lr;
#pragma unroll
      for (int m = 0; m < 4; ++m)
#pragma unroll
        for (int r = 0; r < 4; r += 2) {
          int row = m * 16 + lg * 4 + r;
          uint32_t u = pk[m][n][r >> 1];
          Ms[msoff(row, o)]     = (unsigned short)(u & 0xffffu);
          Ms[msoff(row + 1, o)] = (unsigned short)(u >> 16);
        }
    }
  }
  __syncthreads();

  // ---- GEMM3: Ms2 @ Wc1^T, silu, dot Wc2 -> swred ----
  {
    f32x4 acc[4][2];
#pragma unroll
    for (int m = 0; m < 4; ++m) { f32x4 z = {0.f,0.f,0.f,0.f}; acc[m][0] = z; acc[m][1] = z; }
#pragma unroll
    for (int k0 = 0; k0 < 4; ++k0) {
      bf16x8 b0 = *(const bf16x8*)(W3b + ((w * 32 + lr)      << 7) + k0 * 32 + lg * 8);
      bf16x8 b1 = *(const bf16x8*)(W3b + ((w * 32 + 16 + lr) << 7) + k0 * 32 + lg * 8);
#pragma unroll
      for (int m = 0; m < 4; ++m) {
        int row = m * 16 + lr;
        bf16x8 a = *(const bf16x8*)(&Ms[msoff_slot(row, k0 * 4 + lg)]);
        acc[m][0] = __builtin_amdgcn_mfma_f32_16x16x32_bf16(a, b0, acc[m][0], 0, 0, 0);
        acc[m][1] = __builtin_amdgcn_mfma_f32_16x16x32_bf16(a, b1, acc[m][1], 0, 0, 0);
      }
    }
    float pr[4][4];
#pragma unroll
    for (int m = 0; m < 4; ++m)
#pragma unroll
      for (int r = 0; r < 4; ++r) pr[m][r] = 0.f;
#pragma unroll
    for (int n = 0; n < 2; ++n) {
      int o = w * 32 + n * 16 + lr;
      float b3 = bc1[o], wc = Wc2[o];
#pragma unroll
      for (int m = 0; m < 4; ++m)
#pragma unroll
        for (int r = 0; r < 4; ++r)
          pr[m][r] += silu_f(acc[m][n][r] + b3) * wc;
    }
#pragma unroll
    for (int m = 0; m < 4; ++m)
#pragma unroll
      for (int r = 0; r < 4; ++r) {
        float v = pr[m][r];
        v += __shfl_xor(v, 1); v += __shfl_xor(v, 2);
        v += __shfl_xor(v, 4); v += __shfl_xor(v, 8);
        pr[m][r] = v;
      }
    if (lr == 0) {
#pragma unroll
      for (int m = 0; m < 4; ++m)
#pragma unroll
        for (int r = 0; r < 4; ++r)
          swred[w][m * 16 + lg * 4 + r] = pr[m][r];
    }
  }
  __syncthreads();

  // ---- segmented aggregation (dst-sorted): few atomics per block ----
  const int nv = min(64, E - tbase);
  {
    int c = tid & 127, hf = tid >> 7;
    int e0 = hf * 32;
    int nvh = min(32, nv - e0);
    if (nvh > 0) {
      float run = 0.f;
      int prev = sdst[e0];
#pragma unroll 4
      for (int j = 0; j < nvh; ++j) {
        int e = e0 + j;
        int d = sdst[e];
        float v = bf2f(Ms[msoff(e, c)]);
        if (d != prev) {
          atomicAdd(&aggH[(size_t)prev * 128 + c], run);
          run = 0.f; prev = d;
        }
        run += v;
      }
      atomicAdd(&aggH[(size_t)prev * 128 + c], run);
    }
  }
  if (tid < 6) {
    int c3 = tid % 3, hf = tid / 3;
    int e0 = hf * 32;
    int nvh = min(32, nv - e0);
    if (nvh > 0) {
      float run = 0.f;
      int prev = sdst[e0];
#pragma unroll 4
      for (int j = 0; j < nvh; ++j) {
        int e = e0 + j;
        int d = sdst[e];
        float cwv = swred[0][e] + swred[1][e] + swred[2][e] + swred[3][e];
        if (d != prev) {
          atomicAdd(&coordX[(size_t)prev * 3 + c3], run);
          run = 0.f; prev = d;
        }
        run += sdif[e][c3] * cwv;
      }
      atomicAdd(&coordX[(size_t)prev * 3 + c3], run);
    }
  }
}

// ---- fused node kernel: 64 nodes/block; [h|agg/deg] GEMM -> GEMM -> +h -> LN; x_out ----
__global__ __launch_bounds__(256) void node_kernel(
    const float* __restrict__ h, const float* __restrict__ x,
    const float* __restrict__ bn1, const float* __restrict__ bn2,
    const float* __restrict__ gamma, const float* __restrict__ beta,
    const unsigned short* __restrict__ N1b, const unsigned short* __restrict__ N2b,
    float* __restrict__ aggH, float* __restrict__ coordX,
    const int* __restrict__ deg, int N) {
  __shared__ __align__(16) unsigned short In[64][264];
  __shared__ __align__(16) unsigned short U[64][136];
  __shared__ float scnt[64];

  const int tid  = threadIdx.x;
  const int base = blockIdx.x * 64;
  const int w    = tid >> 6;
  const int lane = tid & 63;
  const int lg   = lane >> 4, lr = lane & 15;
  const int w16  = w * 16;

  if (tid < 64) {
    int n = base + tid;
    scnt[tid] = (n < N) ? fmaxf((float)deg[n], 1.0f) : 1.0f;
  }
  __syncthreads();

#pragma unroll
  for (int it = 0; it < 8; ++it) {
    int idx = tid + it * 256;
    int i = idx >> 5, seg = idx & 31;
    int n = base + i; if (n >= N) n = N - 1;
    float sc = 1.0f;
    const float* p;
    if (seg < 16) { p = h + (size_t)n * 128 + seg * 8; }
    else          { p = aggH + (size_t)n * 128 + (seg - 16) * 8; sc = 1.0f / scnt[i]; }
    float4 a = *(const float4*)p;
    float4 b = *(const float4*)(p + 4);
    uint32_t u0 = cvtpk2(a.x * sc, a.y * sc);
    uint32_t u1 = cvtpk2(a.z * sc, a.w * sc);
    uint32_t u2 = cvtpk2(b.x * sc, b.y * sc);
    uint32_t u3 = cvtpk2(b.z * sc, b.w * sc);
    uint4 v = {u0, u1, u2, u3};
    *(uint4*)&In[i][seg * 8] = v;
  }
  __syncthreads();

  {
    f32x4 acc[8];
#pragma unroll
    for (int n = 0; n < 8; ++n) { f32x4 z = {0.f,0.f,0.f,0.f}; acc[n] = z; }
#pragma unroll
    for (int k0 = 0; k0 < 8; ++k0) {
      bf16x8 a = *(const bf16x8*)(&In[w16 + lr][k0 * 32 + lg * 8]);
#pragma unroll
      for (int n = 0; n < 8; ++n) {
        bf16x8 b = *(const bf16x8*)(N1b + ((n * 16 + lr) << 8) + k0 * 32 + lg * 8);
        acc[n] = __builtin_amdgcn_mfma_f32_16x16x32_bf16(a, b, acc[n], 0, 0, 0);
      }
    }
#pragma unroll
    for (int n = 0; n < 8; ++n) {
      int o = n * 16 + lr;
      float b1 = bn1[o];
#pragma unroll
      for (int r = 0; r < 4; ++r) {
        int me = lg * 4 + r;
        U[w16 + me][o] = f2bf(silu_f(acc[n][r] + b1));
      }
    }
  }

  float* hp = (float*)&In[0][0];   // stride 132 f32
  {
    f32x4 acc[8];
#pragma unroll
    for (int n = 0; n < 8; ++n) { f32x4 z = {0.f,0.f,0.f,0.f}; acc[n] = z; }
#pragma unroll
    for (int k0 = 0; k0 < 4; ++k0) {
      bf16x8 a = *(const bf16x8*)(&U[w16 + lr][k0 * 32 + lg * 8]);
#pragma unroll
      for (int n = 0; n < 8; ++n) {
        bf16x8 b = *(const bf16x8*)(N2b + ((n * 16 + lr) << 7) + k0 * 32 + lg * 8);
        acc[n] = __builtin_amdgcn_mfma_f32_16x16x32_bf16(a, b, acc[n], 0, 0, 0);
      }
    }
#pragma unroll
    for (int n = 0; n < 8; ++n) {
      int o = n * 16 + lr;
      float b2 = bn2[o];
#pragma unroll
      for (int r = 0; r < 4; ++r) {
        int me = w16 + lg * 4 + r;
        int ng = base + me; if (ng >= N) ng = N - 1;
        hp[(size_t)me * 132 + o] = acc[n][r] + b2 + h[(size_t)ng * 128 + o];
      }
    }
  }
  __syncthreads();

  {
    int r = tid >> 2, q = tid & 3;
    int ng = base + r;
    float s = 0.f, s2 = 0.f;
#pragma unroll
    for (int j = 0; j < 32; ++j) {
      float v = hp[(size_t)r * 132 + q * 32 + j];
      s += v; s2 += v * v;
    }
    s  += __shfl_xor(s, 1);  s  += __shfl_xor(s, 2);
    s2 += __shfl_xor(s2, 1); s2 += __shfl_xor(s2, 2);
    float mu  = s * (1.0f / 128.0f);
    float var = s2 * (1.0f / 128.0f) - mu * mu;
    float rs  = rsqrtf(var + 1e-5f);
    if (ng < N) {
#pragma unroll
      for (int j = 0; j < 32; ++j) {
        int o = q * 32 + j;
        float v = (hp[(size_t)r * 132 + o] - mu) * rs * gamma[o] + beta[o];
        aggH[(size_t)ng * 128 + o] = v;
      }
    }
  }

  if (tid < 192) {
    int i = tid / 3, c = tid % 3;
    int n2 = base + i;
    if (n2 < N) {
      size_t off = (size_t)n2 * 3 + c;
      coordX[off] = x[off] + coordX[off] / scnt[i];
    }
  }
}

extern "C" void kernel_launch(void* const* d_in, const int* in_sizes, int n_in,
                              void* d_out, int out_size, void* d_ws, size_t ws_size,
                              hipStream_t stream) {
  const float* h    = (const float*)d_in[0];
  const float* x    = (const float*)d_in[1];
  const int*   ei   = (const int*)d_in[2];
  const float* We1  = (const float*)d_in[3];
  const float* be1  = (const float*)d_in[4];
  const float* We2  = (const float*)d_in[5];
  const float* be2  = (const float*)d_in[6];
  const float* Wn1  = (const float*)d_in[7];
  const float* bn1  = (const float*)d_in[8];
  const float* Wn2  = (const float*)d_in[9];
  const float* bn2  = (const float*)d_in[10];
  const float* Wc1  = (const float*)d_in[11];
  const float* bc1  = (const float*)d_in[12];
  const float* Wc2  = (const float*)d_in[13];
  const float* gamma = (const float*)d_in[14];
  const float* beta  = (const float*)d_in[15];

  int N = in_sizes[0] / 128;
  int E = in_sizes[2] / 2;

  float* aggH   = (float*)d_out;                       // N*128: agg accumulator -> h_out
  float* coordX = (float*)d_out + (size_t)N * 128;     // N*3:   coord accumulator -> x_out

  char* ws = (char*)d_ws;
  size_t off = 0;
  auto alloc = [&](size_t bytes) {
    char* p = ws + off;
    off = (off + bytes + 255) & ~(size_t)255;
    return p;
  };
  unsigned short* PsPd   = (unsigned short*)alloc((size_t)N * 256 * 2);
  unsigned short* W1p    = (unsigned short*)alloc(256 * 128 * 2);
  unsigned short* W2b    = (unsigned short*)alloc(128 * 128 * 2);
  unsigned short* N1b    = (unsigned short*)alloc(128 * 256 * 2);
  unsigned short* N2b    = (unsigned short*)alloc(128 * 128 * 2);
  unsigned short* W3b    = (unsigned short*)alloc(128 * 128 * 2);
  float*          w1c    = (float*)alloc(128 * 4);
  int*            flag   = (int*)alloc(4);
  int*            deg    = (int*)alloc((size_t)N * 4);
  int*            offs   = (int*)alloc(((size_t)N + 1) * 4);
  int*            cursor = (int*)alloc((size_t)N * 4);
  int*            bsum   = (int*)alloc(256 * 4);
  int*            csr_e  = (int*)alloc((size_t)E * 4);
  (void)ws_size;

  int nb = (N + 255) / 256;   // N=50000 -> 196 (<=256 required by scanB)

  hipMemsetAsync(d_out, 0, (size_t)out_size * 4, stream);
  hipMemsetAsync(deg, 0, (size_t)N * 4, stream);

  prep_kernel<<<128, 256, 0, stream>>>(We1, We2, Wn1, Wn2, Wc1, ei,
                                       W1p, W2b, N1b, N2b, W3b, w1c, flag);
  hist_kernel<<<(E + 255) / 256, 256, 0, stream>>>(ei, flag, deg, E);
  scanA_kernel<<<nb, 256, 0, stream>>>(deg, offs, bsum, N);
  scanB_kernel<<<1, 256, 0, stream>>>(bsum, offs, nb, N);
  scanC_kernel<<<nb, 256, 0, stream>>>(bsum, offs, cursor, N);
  scatter_kernel<<<(E + 255) / 256, 256, 0, stream>>>(ei, flag, cursor, csr_e, E);
  proj_kernel<<<(N + 63) / 64, 256, 0, stream>>>(h, be1, W1p, PsPd, N);
  edge_kernel<<<(E + 63) / 64, 256, 0, stream>>>(PsPd, x, ei, w1c, be2, bc1, Wc2,
                                                 W2b, W3b, aggH, coordX, csr_e, flag, E);
  node_kernel<<<(N + 63) / 64, 256, 0, stream>>>(h, x, bn1, bn2, gamma, beta, N1b, N2b,
                                                 aggH, coordX, deg, N);
}

// Round 7
// 402.633 us; speedup vs baseline: 2.8746x; 1.0004x over previous
//
#include <hip/hip_runtime.h>
#include <stdint.h>

using bf16x8 = __attribute__((ext_vector_type(8))) short;
using f32x4  = __attribute__((ext_vector_type(4))) float;

__device__ __forceinline__ unsigned short f2bf(float f) {
  uint32_t x = __float_as_uint(f);
  x += 0x7fffu + ((x >> 16) & 1u);
  return (unsigned short)(x >> 16);
}
__device__ __forceinline__ float bf2f(unsigned short u) {
  return __uint_as_float(((uint32_t)u) << 16);
}
__device__ __forceinline__ uint32_t cvtpk2(float lo, float hi) {
  uint32_t r;
  asm("v_cvt_pk_bf16_f32 %0, %1, %2" : "=v"(r) : "v"(lo), "v"(hi));
  return r;
}
__device__ __forceinline__ float silu_f(float v) {
  float e = __expf(-v);
  return v * __builtin_amdgcn_rcpf(1.0f + e);
}
__device__ __forceinline__ void unpack2(uint32_t u, float& lo, float& hi) {
  lo = __uint_as_float(u << 16);
  hi = __uint_as_float(u & 0xffff0000u);
}

// Ms rotated-swizzle addressing: row stride 136 ushort (272B, b128-aligned).
__device__ __forceinline__ int msoff(int row, int col) {
  return row * 136 + ((((col >> 3) + row * 4) & 15) << 3) + (col & 7);
}
__device__ __forceinline__ int msoff_slot(int row, int slot) {
  return row * 136 + (((slot + row * 4) & 15) << 3);
}

// ---- prep: weights -> bf16, W1p split layout, w1c column, flag sniff ----
__global__ void prep_kernel(const float* __restrict__ We1, const float* __restrict__ We2,
                            const float* __restrict__ Wn1, const float* __restrict__ Wn2,
                            const float* __restrict__ Wc1, const int* __restrict__ ei,
                            unsigned short* __restrict__ W1p, unsigned short* __restrict__ W2b,
                            unsigned short* __restrict__ N1b, unsigned short* __restrict__ N2b,
                            unsigned short* __restrict__ W3b, float* __restrict__ w1c,
                            int* __restrict__ flag) {
  int i = blockIdx.x * 256 + threadIdx.x;      // 0..32767
  if (i < 256 * 128) {
    // W1p[c][k]: c<128 -> Ws row c (We1[c][0:128]); c>=128 -> Wd row c-128 (We1[c-128][128:256])
    int c = i >> 7, k = i & 127;
    W1p[i] = f2bf(We1[(size_t)(c & 127) * 257 + ((c >> 7) << 7) + k]);
    N1b[i] = f2bf(Wn1[i]);
  }
  if (i < 128 * 128) {
    W2b[i] = f2bf(We2[i]);
    W3b[i] = f2bf(Wc1[i]);
    N2b[i] = f2bf(Wn2[i]);
  }
  if (i < 128) w1c[i] = We1[i * 257 + 256];
  if (i == 0) {
    int allz = 1;
    for (int k = 0; k < 64; ++k) allz &= (ei[2 * k + 1] == 0);
    *flag = allz;   // 1 => int64 indices
  }
}

// ---- CSR-order build: hist + 3-kernel parallel scan + scatter ----
__global__ void hist_kernel(const int* __restrict__ ei, const int* __restrict__ flag,
                            int* __restrict__ deg, int E) {
  int e = blockIdx.x * 256 + threadIdx.x;
  if (e >= E) return;
  int d = (*flag) ? (int)((const long long*)ei)[(size_t)E + e] : ei[E + e];
  atomicAdd(&deg[d], 1);
}

__global__ void scanA_kernel(const int* __restrict__ deg, int* __restrict__ offs,
                             int* __restrict__ bsum, int N) {
  __shared__ int sh[256];
  int t = threadIdx.x, idx = blockIdx.x * 256 + t;
  int v = (idx < N) ? deg[idx] : 0;
  sh[t] = v;
  __syncthreads();
#pragma unroll
  for (int d = 1; d < 256; d <<= 1) {
    int u = (t >= d) ? sh[t - d] : 0;
    __syncthreads();
    sh[t] += u;
    __syncthreads();
  }
  if (idx < N) offs[idx] = sh[t] - v;
  if (t == 255) bsum[blockIdx.x] = sh[255];
}

__global__ void scanB_kernel(int* __restrict__ bsum, int* __restrict__ offs,
                             int nb, int N) {
  __shared__ int sh[256];
  int t = threadIdx.x;
  int v = (t < nb) ? bsum[t] : 0;
  sh[t] = v;
  __syncthreads();
#pragma unroll
  for (int d = 1; d < 256; d <<= 1) {
    int u = (t >= d) ? sh[t - d] : 0;
    __syncthreads();
    sh[t] += u;
    __syncthreads();
  }
  bsum[t] = sh[t] - v;
  if (t == 255) offs[N] = sh[255];
}

__global__ void scanC_kernel(const int* __restrict__ bsum, int* __restrict__ offs,
                             int* __restrict__ cursor, int N) {
  int idx = blockIdx.x * 256 + threadIdx.x;
  if (idx < N) {
    int o = offs[idx] + bsum[blockIdx.x];
    offs[idx] = o;
    cursor[idx] = o;
  }
}

__global__ void scatter_kernel(const int* __restrict__ ei, const int* __restrict__ flag,
                               int* __restrict__ cursor, int* __restrict__ csr_e, int E) {
  int e = blockIdx.x * 256 + threadIdx.x;
  if (e >= E) return;
  int d = (*flag) ? (int)((const long long*)ei)[(size_t)E + e] : ei[E + e];
  int pos = atomicAdd(&cursor[d], 1);
  csr_e[pos] = e;
}

// ---- proj: PsPd[n] = [ h[n]@Ws^T + be1 | h[n]@Wd^T ]  (bf16, 256/node) ----
__global__ __launch_bounds__(256) void proj_kernel(
    const float* __restrict__ h, const float* __restrict__ be1,
    const unsigned short* __restrict__ W1p, unsigned short* __restrict__ PsPd, int N) {
  const int tid = threadIdx.x;
  const int base = blockIdx.x * 64;
  const int w = tid >> 6, lane = tid & 63, lg = lane >> 4, lr = lane & 15;

  f32x4 acc[4][4];
#pragma unroll
  for (int m = 0; m < 4; ++m)
#pragma unroll
    for (int n = 0; n < 4; ++n) { f32x4 z = {0.f,0.f,0.f,0.f}; acc[m][n] = z; }

#pragma unroll
  for (int k0 = 0; k0 < 4; ++k0) {
    bf16x8 b[4];
#pragma unroll
    for (int n = 0; n < 4; ++n)
      b[n] = *(const bf16x8*)(W1p + ((w * 64 + n * 16 + lr) << 7) + k0 * 32 + lg * 8);
#pragma unroll
    for (int m = 0; m < 4; ++m) {
      int row = base + m * 16 + lr; if (row >= N) row = N - 1;
      const float* p = h + (size_t)row * 128 + k0 * 32 + lg * 8;
      float4 fa = *(const float4*)p;
      float4 fb = *(const float4*)(p + 4);
      uint32_t u0 = cvtpk2(fa.x, fa.y), u1 = cvtpk2(fa.z, fa.w);
      uint32_t u2 = cvtpk2(fb.x, fb.y), u3 = cvtpk2(fb.z, fb.w);
      union { uint32_t u[4]; bf16x8 v; } cv;
      cv.u[0] = u0; cv.u[1] = u1; cv.u[2] = u2; cv.u[3] = u3;
#pragma unroll
      for (int n = 0; n < 4; ++n)
        acc[m][n] = __builtin_amdgcn_mfma_f32_16x16x32_bf16(cv.v, b[n], acc[m][n], 0, 0, 0);
    }
  }
#pragma unroll
  for (int n = 0; n < 4; ++n) {
    int o = w * 64 + n * 16 + lr;
    float add = (o < 128) ? be1[o] : 0.f;    // fold be1 into Ps half
#pragma unroll
    for (int m = 0; m < 4; ++m)
#pragma unroll
      for (int r = 0; r < 4; ++r) {
        int row = base + m * 16 + lg * 4 + r;
        if (row < N) PsPd[(size_t)row * 256 + o] = f2bf(acc[m][n][r] + add);
      }
  }
}

// ---- fused edge kernel: 64 dst-sorted edges/block; gather Ps/Pd + combine,
//      GEMM2, GEMM3, segmented aggregation ----
__global__ __launch_bounds__(256, 4) void edge_kernel(
    const unsigned short* __restrict__ PsPd, const float* __restrict__ x,
    const int* __restrict__ ei, const float* __restrict__ w1c,
    const float* __restrict__ be2, const float* __restrict__ bc1,
    const float* __restrict__ Wc2,
    const unsigned short* __restrict__ W2b, const unsigned short* __restrict__ W3b,
    float* __restrict__ aggH, float* __restrict__ coordX,
    const int* __restrict__ csr_e, const int* __restrict__ flag, int E) {
  __shared__ __align__(16) unsigned short Ms[64 * 136];  // combine out, then Ms2
  __shared__ float swred[4][64];
  __shared__ int   ssrc[64], sdst[64];
  __shared__ float sds[64];
  __shared__ float sdif[64][3];

  const int tid   = threadIdx.x;
  const int tbase = blockIdx.x * 64;
  const int w = tid >> 6, lane = tid & 63, lg = lane >> 4, lr = lane & 15;

  // phase 0: indices + geometry (dst-sorted via csr_e)
  if (tid < 64) {
    int pos = tbase + tid;
    int s = 0, d = 0;
    if (pos < E) {
      int eid = csr_e[pos];
      if (*flag) {
        s = (int)((const long long*)ei)[eid];
        d = (int)((const long long*)ei)[(size_t)E + eid];
      } else {
        s = ei[eid];
        d = ei[E + eid];
      }
    }
    ssrc[tid] = s; sdst[tid] = d;
    float dx = x[s * 3 + 0] - x[d * 3 + 0];
    float dy = x[s * 3 + 1] - x[d * 3 + 1];
    float dz = x[s * 3 + 2] - x[d * 3 + 2];
    sdif[tid][0] = dx; sdif[tid][1] = dy; sdif[tid][2] = dz;
    sds[tid] = dx * dx + dy * dy + dz * dz;
  }
  __syncthreads();

  // ---- gather Ps[src]/Pd[dst] (issue all 8 loads), combine + silu -> Ms ----
  {
    uint4 av[4], bv[4];
#pragma unroll
    for (int it = 0; it < 4; ++it) {
      int idx = tid + it * 256;            // 0..1023
      int e = idx >> 4, seg = idx & 15;
      av[it] = *(const uint4*)(PsPd + (size_t)ssrc[e] * 256 + seg * 8);
      bv[it] = *(const uint4*)(PsPd + (size_t)sdst[e] * 256 + 128 + seg * 8);
    }
    const float4* w4 = (const float4*)w1c;
#pragma unroll
    for (int it = 0; it < 4; ++it) {
      int idx = tid + it * 256;
      int e = idx >> 4, seg = idx & 15;
      float dsv = sds[e];
      float4 wA = w4[seg * 2], wB = w4[seg * 2 + 1];
      float a0,a1,a2,a3,a4,a5,a6,a7, b0,b1,b2,b3,b4,b5,b6,b7;
      unpack2(((uint32_t*)&av[it])[0], a0, a1);
      unpack2(((uint32_t*)&av[it])[1], a2, a3);
      unpack2(((uint32_t*)&av[it])[2], a4, a5);
      unpack2(((uint32_t*)&av[it])[3], a6, a7);
      unpack2(((uint32_t*)&bv[it])[0], b0, b1);
      unpack2(((uint32_t*)&bv[it])[1], b2, b3);
      unpack2(((uint32_t*)&bv[it])[2], b4, b5);
      unpack2(((uint32_t*)&bv[it])[3], b6, b7);
      float v0 = silu_f(a0 + b0 + dsv * wA.x);
      float v1 = silu_f(a1 + b1 + dsv * wA.y);
      float v2 = silu_f(a2 + b2 + dsv * wA.z);
      float v3 = silu_f(a3 + b3 + dsv * wA.w);
      float v4 = silu_f(a4 + b4 + dsv * wB.x);
      float v5 = silu_f(a5 + b5 + dsv * wB.y);
      float v6 = silu_f(a6 + b6 + dsv * wB.z);
      float v7 = silu_f(a7 + b7 + dsv * wB.w);
      uint4 o;
      o.x = cvtpk2(v0, v1); o.y = cvtpk2(v2, v3);
      o.z = cvtpk2(v4, v5); o.w = cvtpk2(v6, v7);
      *(uint4*)(&Ms[msoff_slot(e, seg)]) = o;
    }
  }
  __syncthreads();

  // ---- GEMM2: Ms @ We2^T (+be2), silu -> Ms2 (same arena) ----
  {
    f32x4 acc[4][2];
#pragma unroll
    for (int m = 0; m < 4; ++m) { f32x4 z = {0.f,0.f,0.f,0.f}; acc[m][0] = z; acc[m][1] = z; }
#pragma unroll
    for (int k0 = 0; k0 < 4; ++k0) {
      bf16x8 b0 = *(const bf16x8*)(W2b + ((w * 32 + lr)      << 7) + k0 * 32 + lg * 8);
      bf16x8 b1 = *(const bf16x8*)(W2b + ((w * 32 + 16 + lr) << 7) + k0 * 32 + lg * 8);
#pragma unroll
      for (int m = 0; m < 4; ++m) {
        int row = m * 16 + lr;
        bf16x8 a = *(const bf16x8*)(&Ms[msoff_slot(row, k0 * 4 + lg)]);
        acc[m][0] = __builtin_amdgcn_mfma_f32_16x16x32_bf16(a, b0, acc[m][0], 0, 0, 0);
        acc[m][1] = __builtin_amdgcn_mfma_f32_16x16x32_bf16(a, b1, acc[m][1], 0, 0, 0);
      }
    }
    uint32_t pk[4][2][2];
#pragma unroll
    for (int n = 0; n < 2; ++n) {
      int o = w * 32 + n * 16 + lr;
      float b2v = be2[o];
#pragma unroll
      for (int m = 0; m < 4; ++m)
#pragma unroll
        for (int r = 0; r < 4; r += 2)
          pk[m][n][r >> 1] = cvtpk2(silu_f(acc[m][n][r] + b2v),
                                    silu_f(acc[m][n][r + 1] + b2v));
    }
    __syncthreads();   // all waves done READING Ms
#pragma unroll
    for (int n = 0; n < 2; ++n) {
      int o = w * 32 + n * 16 + lr;
#pragma unroll
      for (int m = 0; m < 4; ++m)
#pragma unroll
        for (int r = 0; r < 4; r += 2) {
          int row = m * 16 + lg * 4 + r;
          uint32_t u = pk[m][n][r >> 1];
          Ms[msoff(row, o)]     = (unsigned short)(u & 0xffffu);
          Ms[msoff(row + 1, o)] = (unsigned short)(u >> 16);
        }
    }
  }
  __syncthreads();

  // ---- GEMM3: Ms2 @ Wc1^T, silu, dot Wc2 -> swred ----
  {
    f32x4 acc[4][2];
#pragma unroll
    for (int m = 0; m < 4; ++m) { f32x4 z = {0.f,0.f,0.f,0.f}; acc[m][0] = z; acc[m][1] = z; }
#pragma unroll
    for (int k0 = 0; k0 < 4; ++k0) {
      bf16x8 b0 = *(const bf16x8*)(W3b + ((w * 32 + lr)      << 7) + k0 * 32 + lg * 8);
      bf16x8 b1 = *(const bf16x8*)(W3b + ((w * 32 + 16 + lr) << 7) + k0 * 32 + lg * 8);
#pragma unroll
      for (int m = 0; m < 4; ++m) {
        int row = m * 16 + lr;
        bf16x8 a = *(const bf16x8*)(&Ms[msoff_slot(row, k0 * 4 + lg)]);
        acc[m][0] = __builtin_amdgcn_mfma_f32_16x16x32_bf16(a, b0, acc[m][0], 0, 0, 0);
        acc[m][1] = __builtin_amdgcn_mfma_f32_16x16x32_bf16(a, b1, acc[m][1], 0, 0, 0);
      }
    }
    float pr[4][4];
#pragma unroll
    for (int m = 0; m < 4; ++m)
#pragma unroll
      for (int r = 0; r < 4; ++r) pr[m][r] = 0.f;
#pragma unroll
    for (int n = 0; n < 2; ++n) {
      int o = w * 32 + n * 16 + lr;
      float b3 = bc1[o], wc = Wc2[o];
#pragma unroll
      for (int m = 0; m < 4; ++m)
#pragma unroll
        for (int r = 0; r < 4; ++r)
          pr[m][r] += silu_f(acc[m][n][r] + b3) * wc;
    }
#pragma unroll
    for (int m = 0; m < 4; ++m)
#pragma unroll
      for (int r = 0; r < 4; ++r) {
        float v = pr[m][r];
        v += __shfl_xor(v, 1); v += __shfl_xor(v, 2);
        v += __shfl_xor(v, 4); v += __shfl_xor(v, 8);
        pr[m][r] = v;
      }
    if (lr == 0) {
#pragma unroll
      for (int m = 0; m < 4; ++m)
#pragma unroll
        for (int r = 0; r < 4; ++r)
          swred[w][m * 16 + lg * 4 + r] = pr[m][r];
    }
  }
  __syncthreads();

  // ---- segmented aggregation (dst-sorted): few atomics per block ----
  const int nv = min(64, E - tbase);
  {
    int c = tid & 127, hf = tid >> 7;
    int e0 = hf * 32;
    int nvh = min(32, nv - e0);
    if (nvh > 0) {
      float run = 0.f;
      int prev = sdst[e0];
#pragma unroll 4
      for (int j = 0; j < nvh; ++j) {
        int e = e0 + j;
        int d = sdst[e];
        float v = bf2f(Ms[msoff(e, c)]);
        if (d != prev) {
          atomicAdd(&aggH[(size_t)prev * 128 + c], run);
          run = 0.f; prev = d;
        }
        run += v;
      }
      atomicAdd(&aggH[(size_t)prev * 128 + c], run);
    }
  }
  if (tid < 6) {
    int c3 = tid % 3, hf = tid / 3;
    int e0 = hf * 32;
    int nvh = min(32, nv - e0);
    if (nvh > 0) {
      float run = 0.f;
      int prev = sdst[e0];
#pragma unroll 4
      for (int j = 0; j < nvh; ++j) {
        int e = e0 + j;
        int d = sdst[e];
        float cwv = swred[0][e] + swred[1][e] + swred[2][e] + swred[3][e];
        if (d != prev) {
          atomicAdd(&coordX[(size_t)prev * 3 + c3], run);
          run = 0.f; prev = d;
        }
        run += sdif[e][c3] * cwv;
      }
      atomicAdd(&coordX[(size_t)prev * 3 + c3], run);
    }
  }
}

// ---- fused node kernel: 64 nodes/block; [h|agg/deg] GEMM -> GEMM -> +h -> LN; x_out ----
__global__ __launch_bounds__(256) void node_kernel(
    const float* __restrict__ h, const float* __restrict__ x,
    const float* __restrict__ bn1, const float* __restrict__ bn2,
    const float* __restrict__ gamma, const float* __restrict__ beta,
    const unsigned short* __restrict__ N1b, const unsigned short* __restrict__ N2b,
    float* __restrict__ aggH, float* __restrict__ coordX,
    const int* __restrict__ deg, int N) {
  __shared__ __align__(16) unsigned short In[64][264];
  __shared__ __align__(16) unsigned short U[64][136];
  __shared__ float scnt[64];

  const int tid  = threadIdx.x;
  const int base = blockIdx.x * 64;
  const int w    = tid >> 6;
  const int lane = tid & 63;
  const int lg   = lane >> 4, lr = lane & 15;
  const int w16  = w * 16;

  if (tid < 64) {
    int n = base + tid;
    scnt[tid] = (n < N) ? fmaxf((float)deg[n], 1.0f) : 1.0f;
  }
  __syncthreads();

#pragma unroll
  for (int it = 0; it < 8; ++it) {
    int idx = tid + it * 256;
    int i = idx >> 5, seg = idx & 31;
    int n = base + i; if (n >= N) n = N - 1;
    float sc = 1.0f;
    const float* p;
    if (seg < 16) { p = h + (size_t)n * 128 + seg * 8; }
    else          { p = aggH + (size_t)n * 128 + (seg - 16) * 8; sc = 1.0f / scnt[i]; }
    float4 a = *(const float4*)p;
    float4 b = *(const float4*)(p + 4);
    uint32_t u0 = cvtpk2(a.x * sc, a.y * sc);
    uint32_t u1 = cvtpk2(a.z * sc, a.w * sc);
    uint32_t u2 = cvtpk2(b.x * sc, b.y * sc);
    uint32_t u3 = cvtpk2(b.z * sc, b.w * sc);
    uint4 v = {u0, u1, u2, u3};
    *(uint4*)&In[i][seg * 8] = v;
  }
  __syncthreads();

  {
    f32x4 acc[8];
#pragma unroll
    for (int n = 0; n < 8; ++n) { f32x4 z = {0.f,0.f,0.f,0.f}; acc[n] = z; }
#pragma unroll
    for (int k0 = 0; k0 < 8; ++k0) {
      bf16x8 a = *(const bf16x8*)(&In[w16 + lr][k0 * 32 + lg * 8]);
#pragma unroll
      for (int n = 0; n < 8; ++n) {
        bf16x8 b = *(const bf16x8*)(N1b + ((n * 16 + lr) << 8) + k0 * 32 + lg * 8);
        acc[n] = __builtin_amdgcn_mfma_f32_16x16x32_bf16(a, b, acc[n], 0, 0, 0);
      }
    }
#pragma unroll
    for (int n = 0; n < 8; ++n) {
      int o = n * 16 + lr;
      float b1 = bn1[o];
#pragma unroll
      for (int r = 0; r < 4; ++r) {
        int me = lg * 4 + r;
        U[w16 + me][o] = f2bf(silu_f(acc[n][r] + b1));
      }
    }
  }

  float* hp = (float*)&In[0][0];   // stride 132 f32
  {
    f32x4 acc[8];
#pragma unroll
    for (int n = 0; n < 8; ++n) { f32x4 z = {0.f,0.f,0.f,0.f}; acc[n] = z; }
#pragma unroll
    for (int k0 = 0; k0 < 4; ++k0) {
      bf16x8 a = *(const bf16x8*)(&U[w16 + lr][k0 * 32 + lg * 8]);
#pragma unroll
      for (int n = 0; n < 8; ++n) {
        bf16x8 b = *(const bf16x8*)(N2b + ((n * 16 + lr) << 7) + k0 * 32 + lg * 8);
        acc[n] = __builtin_amdgcn_mfma_f32_16x16x32_bf16(a, b, acc[n], 0, 0, 0);
      }
    }
#pragma unroll
    for (int n = 0; n < 8; ++n) {
      int o = n * 16 + lr;
      float b2 = bn2[o];
#pragma unroll
      for (int r = 0; r < 4; ++r) {
        int me = w16 + lg * 4 + r;
        int ng = base + me; if (ng >= N) ng = N - 1;
        hp[(size_t)me * 132 + o] = acc[n][r] + b2 + h[(size_t)ng * 128 + o];
      }
    }
  }
  __syncthreads();

  {
    int r = tid >> 2, q = tid & 3;
    int ng = base + r;
    float s = 0.f, s2 = 0.f;
#pragma unroll
    for (int j = 0; j < 32; ++j) {
      float v = hp[(size_t)r * 132 + q * 32 + j];
      s += v; s2 += v * v;
    }
    s  += __shfl_xor(s, 1);  s  += __shfl_xor(s, 2);
    s2 += __shfl_xor(s2, 1); s2 += __shfl_xor(s2, 2);
    float mu  = s * (1.0f / 128.0f);
    float var = s2 * (1.0f / 128.0f) - mu * mu;
    float rs  = rsqrtf(var + 1e-5f);
    if (ng < N) {
#pragma unroll
      for (int j = 0; j < 32; ++j) {
        int o = q * 32 + j;
        float v = (hp[(size_t)r * 132 + o] - mu) * rs * gamma[o] + beta[o];
        aggH[(size_t)ng * 128 + o] = v;
      }
    }
  }

  if (tid < 192) {
    int i = tid / 3, c = tid % 3;
    int n2 = base + i;
    if (n2 < N) {
      size_t off = (size_t)n2 * 3 + c;
      coordX[off] = x[off] + coordX[off] / scnt[i];
    }
  }
}

extern "C" void kernel_launch(void* const* d_in, const int* in_sizes, int n_in,
                              void* d_out, int out_size, void* d_ws, size_t ws_size,
                              hipStream_t stream) {
  const float* h    = (const float*)d_in[0];
  const float* x    = (const float*)d_in[1];
  const int*   ei   = (const int*)d_in[2];
  const float* We1  = (const float*)d_in[3];
  const float* be1  = (const float*)d_in[4];
  const float* We2  = (const float*)d_in[5];
  const float* be2  = (const float*)d_in[6];
  const float* Wn1  = (const float*)d_in[7];
  const float* bn1  = (const float*)d_in[8];
  const float* Wn2  = (const float*)d_in[9];
  const float* bn2  = (const float*)d_in[10];
  const float* Wc1  = (const float*)d_in[11];
  const float* bc1  = (const float*)d_in[12];
  const float* Wc2  = (const float*)d_in[13];
  const float* gamma = (const float*)d_in[14];
  const float* beta  = (const float*)d_in[15];

  int N = in_sizes[0] / 128;
  int E = in_sizes[2] / 2;

  float* aggH   = (float*)d_out;                       // N*128: agg accumulator -> h_out
  float* coordX = (float*)d_out + (size_t)N * 128;     // N*3:   coord accumulator -> x_out

  char* ws = (char*)d_ws;
  size_t off = 0;
  auto alloc = [&](size_t bytes) {
    char* p = ws + off;
    off = (off + bytes + 255) & ~(size_t)255;
    return p;
  };
  unsigned short* PsPd   = (unsigned short*)alloc((size_t)N * 256 * 2);
  unsigned short* W1p    = (unsigned short*)alloc(256 * 128 * 2);
  unsigned short* W2b    = (unsigned short*)alloc(128 * 128 * 2);
  unsigned short* N1b    = (unsigned short*)alloc(128 * 256 * 2);
  unsigned short* N2b    = (unsigned short*)alloc(128 * 128 * 2);
  unsigned short* W3b    = (unsigned short*)alloc(128 * 128 * 2);
  float*          w1c    = (float*)alloc(128 * 4);
  int*            flag   = (int*)alloc(4);
  int*            deg    = (int*)alloc((size_t)N * 4);
  int*            offs   = (int*)alloc(((size_t)N + 1) * 4);
  int*            cursor = (int*)alloc((size_t)N * 4);
  int*            bsum   = (int*)alloc(256 * 4);
  int*            csr_e  = (int*)alloc((size_t)E * 4);
  (void)ws_size;

  int nb = (N + 255) / 256;   // N=50000 -> 196 (<=256 required by scanB)

  hipMemsetAsync(d_out, 0, (size_t)out_size * 4, stream);
  hipMemsetAsync(deg, 0, (size_t)N * 4, stream);

  prep_kernel<<<128, 256, 0, stream>>>(We1, We2, Wn1, Wn2, Wc1, ei,
                                       W1p, W2b, N1b, N2b, W3b, w1c, flag);
  hist_kernel<<<(E + 255) / 256, 256, 0, stream>>>(ei, flag, deg, E);
  scanA_kernel<<<nb, 256, 0, stream>>>(deg, offs, bsum, N);
  scanB_kernel<<<1, 256, 0, stream>>>(bsum, offs, nb, N);
  scanC_kernel<<<nb, 256, 0, stream>>>(bsum, offs, cursor, N);
  scatter_kernel<<<(E + 255) / 256, 256, 0, stream>>>(ei, flag, cursor, csr_e, E);
  proj_kernel<<<(N + 63) / 64, 256, 0, stream>>>(h, be1, W1p, PsPd, N);
  edge_kernel<<<(E + 63) / 64, 256, 0, stream>>>(PsPd, x, ei, w1c, be2, bc1, Wc2,
                                                 W2b, W3b, aggH, coordX, csr_e, flag, E);
  node_kernel<<<(N + 63) / 64, 256, 0, stream>>>(h, x, bn1, bn2, gamma, beta, N1b, N2b,
                                                 aggH, coordX, deg, N);
}

// Round 8
// 401.515 us; speedup vs baseline: 2.8826x; 1.0028x over previous
//
#include <hip/hip_runtime.h>
#include <stdint.h>

using bf16x8 = __attribute__((ext_vector_type(8))) short;
using f32x4  = __attribute__((ext_vector_type(4))) float;

__device__ __forceinline__ unsigned short f2bf(float f) {
  uint32_t x = __float_as_uint(f);
  x += 0x7fffu + ((x >> 16) & 1u);
  return (unsigned short)(x >> 16);
}
__device__ __forceinline__ float bf2f(unsigned short u) {
  return __uint_as_float(((uint32_t)u) << 16);
}
__device__ __forceinline__ uint32_t cvtpk2(float lo, float hi) {
  uint32_t r;
  asm("v_cvt_pk_bf16_f32 %0, %1, %2" : "=v"(r) : "v"(lo), "v"(hi));
  return r;
}
__device__ __forceinline__ float silu_f(float v) {
  float e = __expf(-v);
  return v * __builtin_amdgcn_rcpf(1.0f + e);
}
__device__ __forceinline__ void unpack2(uint32_t u, float& lo, float& hi) {
  lo = __uint_as_float(u << 16);
  hi = __uint_as_float(u & 0xffff0000u);
}

// Ms rotated-swizzle addressing: row stride 136 ushort (272B, b128-aligned).
__device__ __forceinline__ int msoff(int row, int col) {
  return row * 136 + ((((col >> 3) + row * 4) & 15) << 3) + (col & 7);
}
__device__ __forceinline__ int msoff_slot(int row, int slot) {
  return row * 136 + (((slot + row * 4) & 15) << 3);
}

// ---- prep: weights -> bf16, W1p split layout, w1c column, flag sniff ----
__global__ void prep_kernel(const float* __restrict__ We1, const float* __restrict__ We2,
                            const float* __restrict__ Wn1, const float* __restrict__ Wn2,
                            const float* __restrict__ Wc1, const int* __restrict__ ei,
                            unsigned short* __restrict__ W1p, unsigned short* __restrict__ W2b,
                            unsigned short* __restrict__ N1b, unsigned short* __restrict__ N2b,
                            unsigned short* __restrict__ W3b, float* __restrict__ w1c,
                            int* __restrict__ flag) {
  int i = blockIdx.x * 256 + threadIdx.x;      // 0..32767
  if (i < 256 * 128) {
    // W1p[c][k]: c<128 -> Ws row c (We1[c][0:128]); c>=128 -> Wd row c-128 (We1[c-128][128:256])
    int c = i >> 7, k = i & 127;
    W1p[i] = f2bf(We1[(size_t)(c & 127) * 257 + ((c >> 7) << 7) + k]);
    N1b[i] = f2bf(Wn1[i]);
  }
  if (i < 128 * 128) {
    W2b[i] = f2bf(We2[i]);
    W3b[i] = f2bf(Wc1[i]);
    N2b[i] = f2bf(Wn2[i]);
  }
  if (i < 128) w1c[i] = We1[i * 257 + 256];
  if (i == 0) {
    int allz = 1;
    for (int k = 0; k < 64; ++k) allz &= (ei[2 * k + 1] == 0);
    *flag = allz;   // 1 => int64 indices
  }
}

// ---- CSR-order build: hist + 3-kernel parallel scan + scatter ----
__global__ void hist_kernel(const int* __restrict__ ei, const int* __restrict__ flag,
                            int* __restrict__ deg, int E) {
  int e = blockIdx.x * 256 + threadIdx.x;
  if (e >= E) return;
  int d = (*flag) ? (int)((const long long*)ei)[(size_t)E + e] : ei[E + e];
  atomicAdd(&deg[d], 1);
}

__global__ void scanA_kernel(const int* __restrict__ deg, int* __restrict__ offs,
                             int* __restrict__ bsum, int N) {
  __shared__ int sh[256];
  int t = threadIdx.x, idx = blockIdx.x * 256 + t;
  int v = (idx < N) ? deg[idx] : 0;
  sh[t] = v;
  __syncthreads();
#pragma unroll
  for (int d = 1; d < 256; d <<= 1) {
    int u = (t >= d) ? sh[t - d] : 0;
    __syncthreads();
    sh[t] += u;
    __syncthreads();
  }
  if (idx < N) offs[idx] = sh[t] - v;
  if (t == 255) bsum[blockIdx.x] = sh[255];
}

__global__ void scanB_kernel(int* __restrict__ bsum, int* __restrict__ offs,
                             int nb, int N) {
  __shared__ int sh[256];
  int t = threadIdx.x;
  int v = (t < nb) ? bsum[t] : 0;
  sh[t] = v;
  __syncthreads();
#pragma unroll
  for (int d = 1; d < 256; d <<= 1) {
    int u = (t >= d) ? sh[t - d] : 0;
    __syncthreads();
    sh[t] += u;
    __syncthreads();
  }
  bsum[t] = sh[t] - v;
  if (t == 255) offs[N] = sh[255];
}

__global__ void scanC_kernel(const int* __restrict__ bsum, int* __restrict__ offs,
                             int* __restrict__ cursor, int N) {
  int idx = blockIdx.x * 256 + threadIdx.x;
  if (idx < N) {
    int o = offs[idx] + bsum[blockIdx.x];
    offs[idx] = o;
    cursor[idx] = o;
  }
}

__global__ void scatter_kernel(const int* __restrict__ ei, const int* __restrict__ flag,
                               int* __restrict__ cursor, int* __restrict__ csr_e, int E) {
  int e = blockIdx.x * 256 + threadIdx.x;
  if (e >= E) return;
  int d = (*flag) ? (int)((const long long*)ei)[(size_t)E + e] : ei[E + e];
  int pos = atomicAdd(&cursor[d], 1);
  csr_e[pos] = e;
}

// ---- proj: PsPd[n] = [ h[n]@Ws^T + be1 | h[n]@Wd^T ]  (bf16, 256/node) ----
__global__ __launch_bounds__(256) void proj_kernel(
    const float* __restrict__ h, const float* __restrict__ be1,
    const unsigned short* __restrict__ W1p, unsigned short* __restrict__ PsPd, int N) {
  const int tid = threadIdx.x;
  const int base = blockIdx.x * 64;
  const int w = tid >> 6, lane = tid & 63, lg = lane >> 4, lr = lane & 15;

  f32x4 acc[4][4];
#pragma unroll
  for (int m = 0; m < 4; ++m)
#pragma unroll
    for (int n = 0; n < 4; ++n) { f32x4 z = {0.f,0.f,0.f,0.f}; acc[m][n] = z; }

#pragma unroll
  for (int k0 = 0; k0 < 4; ++k0) {
    bf16x8 b[4];
#pragma unroll
    for (int n = 0; n < 4; ++n)
      b[n] = *(const bf16x8*)(W1p + ((w * 64 + n * 16 + lr) << 7) + k0 * 32 + lg * 8);
#pragma unroll
    for (int m = 0; m < 4; ++m) {
      int row = base + m * 16 + lr; if (row >= N) row = N - 1;
      const float* p = h + (size_t)row * 128 + k0 * 32 + lg * 8;
      float4 fa = *(const float4*)p;
      float4 fb = *(const float4*)(p + 4);
      uint32_t u0 = cvtpk2(fa.x, fa.y), u1 = cvtpk2(fa.z, fa.w);
      uint32_t u2 = cvtpk2(fb.x, fb.y), u3 = cvtpk2(fb.z, fb.w);
      union { uint32_t u[4]; bf16x8 v; } cv;
      cv.u[0] = u0; cv.u[1] = u1; cv.u[2] = u2; cv.u[3] = u3;
#pragma unroll
      for (int n = 0; n < 4; ++n)
        acc[m][n] = __builtin_amdgcn_mfma_f32_16x16x32_bf16(cv.v, b[n], acc[m][n], 0, 0, 0);
    }
  }
#pragma unroll
  for (int n = 0; n < 4; ++n) {
    int o = w * 64 + n * 16 + lr;
    float add = (o < 128) ? be1[o] : 0.f;    // fold be1 into Ps half
#pragma unroll
    for (int m = 0; m < 4; ++m)
#pragma unroll
      for (int r = 0; r < 4; ++r) {
        int row = base + m * 16 + lg * 4 + r;
        if (row < N) PsPd[(size_t)row * 256 + o] = f2bf(acc[m][n][r] + add);
      }
  }
}

// ---- fused edge kernel: 64 dst-sorted edges/block; gather Ps/Pd + combine,
//      GEMM2, GEMM3, segmented aggregation ----
__global__ __launch_bounds__(256, 4) void edge_kernel(
    const unsigned short* __restrict__ PsPd, const float* __restrict__ x,
    const int* __restrict__ ei, const float* __restrict__ w1c,
    const float* __restrict__ be2, const float* __restrict__ bc1,
    const float* __restrict__ Wc2,
    const unsigned short* __restrict__ W2b, const unsigned short* __restrict__ W3b,
    float* __restrict__ aggH, float* __restrict__ coordX,
    const int* __restrict__ csr_e, const int* __restrict__ flag, int E) {
  __shared__ __align__(16) unsigned short Ms[64 * 136];  // combine out, then Ms2
  __shared__ float swred[4][64];
  __shared__ int   ssrc[64], sdst[64];
  __shared__ float sds[64];
  __shared__ float sdif[64][3];

  const int tid   = threadIdx.x;
  const int tbase = blockIdx.x * 64;
  const int w = tid >> 6, lane = tid & 63, lg = lane >> 4, lr = lane & 15;

  // phase 0: indices + geometry (dst-sorted via csr_e)
  if (tid < 64) {
    int pos = tbase + tid;
    int s = 0, d = 0;
    if (pos < E) {
      int eid = csr_e[pos];
      if (*flag) {
        s = (int)((const long long*)ei)[eid];
        d = (int)((const long long*)ei)[(size_t)E + eid];
      } else {
        s = ei[eid];
        d = ei[E + eid];
      }
    }
    ssrc[tid] = s; sdst[tid] = d;
    float dx = x[s * 3 + 0] - x[d * 3 + 0];
    float dy = x[s * 3 + 1] - x[d * 3 + 1];
    float dz = x[s * 3 + 2] - x[d * 3 + 2];
    sdif[tid][0] = dx; sdif[tid][1] = dy; sdif[tid][2] = dz;
    sds[tid] = dx * dx + dy * dy + dz * dz;
  }
  __syncthreads();

  // ---- gather Ps[src]/Pd[dst] (issue all 8 loads), combine + silu -> Ms ----
  {
    uint4 av[4], bv[4];
#pragma unroll
    for (int it = 0; it < 4; ++it) {
      int idx = tid + it * 256;            // 0..1023
      int e = idx >> 4, seg = idx & 15;
      av[it] = *(const uint4*)(PsPd + (size_t)ssrc[e] * 256 + seg * 8);
      bv[it] = *(const uint4*)(PsPd + (size_t)sdst[e] * 256 + 128 + seg * 8);
    }
    const float4* w4 = (const float4*)w1c;
#pragma unroll
    for (int it = 0; it < 4; ++it) {
      int idx = tid + it * 256;
      int e = idx >> 4, seg = idx & 15;
      float dsv = sds[e];
      float4 wA = w4[seg * 2], wB = w4[seg * 2 + 1];
      float a0,a1,a2,a3,a4,a5,a6,a7, b0,b1,b2,b3,b4,b5,b6,b7;
      unpack2(((uint32_t*)&av[it])[0], a0, a1);
      unpack2(((uint32_t*)&av[it])[1], a2, a3);
      unpack2(((uint32_t*)&av[it])[2], a4, a5);
      unpack2(((uint32_t*)&av[it])[3], a6, a7);
      unpack2(((uint32_t*)&bv[it])[0], b0, b1);
      unpack2(((uint32_t*)&bv[it])[1], b2, b3);
      unpack2(((uint32_t*)&bv[it])[2], b4, b5);
      unpack2(((uint32_t*)&bv[it])[3], b6, b7);
      float v0 = silu_f(a0 + b0 + dsv * wA.x);
      float v1 = silu_f(a1 + b1 + dsv * wA.y);
      float v2 = silu_f(a2 + b2 + dsv * wA.z);
      float v3 = silu_f(a3 + b3 + dsv * wA.w);
      float v4 = silu_f(a4 + b4 + dsv * wB.x);
      float v5 = silu_f(a5 + b5 + dsv * wB.y);
      float v6 = silu_f(a6 + b6 + dsv * wB.z);
      float v7 = silu_f(a7 + b7 + dsv * wB.w);
      uint4 o;
      o.x = cvtpk2(v0, v1); o.y = cvtpk2(v2, v3);
      o.z = cvtpk2(v4, v5); o.w = cvtpk2(v6, v7);
      *(uint4*)(&Ms[msoff_slot(e, seg)]) = o;
    }
  }
  __syncthreads();

  // ---- GEMM2: Ms @ We2^T (+be2), silu -> Ms2 (same arena) ----
  {
    f32x4 acc[4][2];
#pragma unroll
    for (int m = 0; m < 4; ++m) { f32x4 z = {0.f,0.f,0.f,0.f}; acc[m][0] = z; acc[m][1] = z; }
#pragma unroll
    for (int k0 = 0; k0 < 4; ++k0) {
      bf16x8 b0 = *(const bf16x8*)(W2b + ((w * 32 + lr)      << 7) + k0 * 32 + lg * 8);
      bf16x8 b1 = *(const bf16x8*)(W2b + ((w * 32 + 16 + lr) << 7) + k0 * 32 + lg * 8);
#pragma unroll
      for (int m = 0; m < 4; ++m) {
        int row = m * 16 + lr;
        bf16x8 a = *(const bf16x8*)(&Ms[msoff_slot(row, k0 * 4 + lg)]);
        acc[m][0] = __builtin_amdgcn_mfma_f32_16x16x32_bf16(a, b0, acc[m][0], 0, 0, 0);
        acc[m][1] = __builtin_amdgcn_mfma_f32_16x16x32_bf16(a, b1, acc[m][1], 0, 0, 0);
      }
    }
    uint32_t pk[4][2][2];
#pragma unroll
    for (int n = 0; n < 2; ++n) {
      int o = w * 32 + n * 16 + lr;
      float b2v = be2[o];
#pragma unroll
      for (int m = 0; m < 4; ++m)
#pragma unroll
        for (int r = 0; r < 4; r += 2)
          pk[m][n][r >> 1] = cvtpk2(silu_f(acc[m][n][r] + b2v),
                                    silu_f(acc[m][n][r + 1] + b2v));
    }
    __syncthreads();   // all waves done READING Ms
#pragma unroll
    for (int n = 0; n < 2; ++n) {
      int o = w * 32 + n * 16 + lr;
#pragma unroll
      for (int m = 0; m < 4; ++m)
#pragma unroll
        for (int r = 0; r < 4; r += 2) {
          int row = m * 16 + lg * 4 + r;
          uint32_t u = pk[m][n][r >> 1];
          Ms[msoff(row, o)]     = (unsigned short)(u & 0xffffu);
          Ms[msoff(row + 1, o)] = (unsigned short)(u >> 16);
        }
    }
  }
  __syncthreads();

  // ---- GEMM3: Ms2 @ Wc1^T, silu, dot Wc2 -> swred ----
  {
    f32x4 acc[4][2];
#pragma unroll
    for (int m = 0; m < 4; ++m) { f32x4 z = {0.f,0.f,0.f,0.f}; acc[m][0] = z; acc[m][1] = z; }
#pragma unroll
    for (int k0 = 0; k0 < 4; ++k0) {
      bf16x8 b0 = *(const bf16x8*)(W3b + ((w * 32 + lr)      << 7) + k0 * 32 + lg * 8);
      bf16x8 b1 = *(const bf16x8*)(W3b + ((w * 32 + 16 + lr) << 7) + k0 * 32 + lg * 8);
#pragma unroll
      for (int m = 0; m < 4; ++m) {
        int row = m * 16 + lr;
        bf16x8 a = *(const bf16x8*)(&Ms[msoff_slot(row, k0 * 4 + lg)]);
        acc[m][0] = __builtin_amdgcn_mfma_f32_16x16x32_bf16(a, b0, acc[m][0], 0, 0, 0);
        acc[m][1] = __builtin_amdgcn_mfma_f32_16x16x32_bf16(a, b1, acc[m][1], 0, 0, 0);
      }
    }
    float pr[4][4];
#pragma unroll
    for (int m = 0; m < 4; ++m)
#pragma unroll
      for (int r = 0; r < 4; ++r) pr[m][r] = 0.f;
#pragma unroll
    for (int n = 0; n < 2; ++n) {
      int o = w * 32 + n * 16 + lr;
      float b3 = bc1[o], wc = Wc2[o];
#pragma unroll
      for (int m = 0; m < 4; ++m)
#pragma unroll
        for (int r = 0; r < 4; ++r)
          pr[m][r] += silu_f(acc[m][n][r] + b3) * wc;
    }
#pragma unroll
    for (int m = 0; m < 4; ++m)
#pragma unroll
      for (int r = 0; r < 4; ++r) {
        float v = pr[m][r];
        v += __shfl_xor(v, 1); v += __shfl_xor(v, 2);
        v += __shfl_xor(v, 4); v += __shfl_xor(v, 8);
        pr[m][r] = v;
      }
    if (lr == 0) {
#pragma unroll
      for (int m = 0; m < 4; ++m)
#pragma unroll
        for (int r = 0; r < 4; ++r)
          swred[w][m * 16 + lg * 4 + r] = pr[m][r];
    }
  }
  __syncthreads();

  // ---- segmented aggregation (dst-sorted): few atomics per block ----
  const int nv = min(64, E - tbase);
  {
    int c = tid & 127, hf = tid >> 7;
    int e0 = hf * 32;
    int nvh = min(32, nv - e0);
    if (nvh > 0) {
      float run = 0.f;
      int prev = sdst[e0];
#pragma unroll 4
      for (int j = 0; j < nvh; ++j) {
        int e = e0 + j;
        int d = sdst[e];
        float v = bf2f(Ms[msoff(e, c)]);
        if (d != prev) {
          atomicAdd(&aggH[(size_t)prev * 128 + c], run);
          run = 0.f; prev = d;
        }
        run += v;
      }
      atomicAdd(&aggH[(size_t)prev * 128 + c], run);
    }
  }
  if (tid < 6) {
    int c3 = tid % 3, hf = tid / 3;
    int e0 = hf * 32;
    int nvh = min(32, nv - e0);
    if (nvh > 0) {
      float run = 0.f;
      int prev = sdst[e0];
#pragma unroll 4
      for (int j = 0; j < nvh; ++j) {
        int e = e0 + j;
        int d = sdst[e];
        float cwv = swred[0][e] + swred[1][e] + swred[2][e] + swred[3][e];
        if (d != prev) {
          atomicAdd(&coordX[(size_t)prev * 3 + c3], run);
          run = 0.f; prev = d;
        }
        run += sdif[e][c3] * cwv;
      }
      atomicAdd(&coordX[(size_t)prev * 3 + c3], run);
    }
  }
}

// ---- fused node kernel: 64 nodes/block; [h|agg/deg] GEMM -> GEMM -> +h -> LN; x_out ----
__global__ __launch_bounds__(256) void node_kernel(
    const float* __restrict__ h, const float* __restrict__ x,
    const float* __restrict__ bn1, const float* __restrict__ bn2,
    const float* __restrict__ gamma, const float* __restrict__ beta,
    const unsigned short* __restrict__ N1b, const unsigned short* __restrict__ N2b,
    float* __restrict__ aggH, float* __restrict__ coordX,
    const int* __restrict__ deg, int N) {
  __shared__ __align__(16) unsigned short In[64][264];
  __shared__ __align__(16) unsigned short U[64][136];
  __shared__ float scnt[64];

  const int tid  = threadIdx.x;
  const int base = blockIdx.x * 64;
  const int w    = tid >> 6;
  const int lane = tid & 63;
  const int lg   = lane >> 4, lr = lane & 15;
  const int w16  = w * 16;

  if (tid < 64) {
    int n = base + tid;
    scnt[tid] = (n < N) ? fmaxf((float)deg[n], 1.0f) : 1.0f;
  }
  __syncthreads();

#pragma unroll
  for (int it = 0; it < 8; ++it) {
    int idx = tid + it * 256;
    int i = idx >> 5, seg = idx & 31;
    int n = base + i; if (n >= N) n = N - 1;
    float sc = 1.0f;
    const float* p;
    if (seg < 16) { p = h + (size_t)n * 128 + seg * 8; }
    else          { p = aggH + (size_t)n * 128 + (seg - 16) * 8; sc = 1.0f / scnt[i]; }
    float4 a = *(const float4*)p;
    float4 b = *(const float4*)(p + 4);
    uint32_t u0 = cvtpk2(a.x * sc, a.y * sc);
    uint32_t u1 = cvtpk2(a.z * sc, a.w * sc);
    uint32_t u2 = cvtpk2(b.x * sc, b.y * sc);
    uint32_t u3 = cvtpk2(b.z * sc, b.w * sc);
    uint4 v = {u0, u1, u2, u3};
    *(uint4*)&In[i][seg * 8] = v;
  }
  __syncthreads();

  {
    f32x4 acc[8];
#pragma unroll
    for (int n = 0; n < 8; ++n) { f32x4 z = {0.f,0.f,0.f,0.f}; acc[n] = z; }
#pragma unroll
    for (int k0 = 0; k0 < 8; ++k0) {
      bf16x8 a = *(const bf16x8*)(&In[w16 + lr][k0 * 32 + lg * 8]);
#pragma unroll
      for (int n = 0; n < 8; ++n) {
        bf16x8 b = *(const bf16x8*)(N1b + ((n * 16 + lr) << 8) + k0 * 32 + lg * 8);
        acc[n] = __builtin_amdgcn_mfma_f32_16x16x32_bf16(a, b, acc[n], 0, 0, 0);
      }
    }
#pragma unroll
    for (int n = 0; n < 8; ++n) {
      int o = n * 16 + lr;
      float b1 = bn1[o];
#pragma unroll
      for (int r = 0; r < 4; ++r) {
        int me = lg * 4 + r;
        U[w16 + me][o] = f2bf(silu_f(acc[n][r] + b1));
      }
    }
  }

  float* hp = (float*)&In[0][0];   // stride 132 f32
  {
    f32x4 acc[8];
#pragma unroll
    for (int n = 0; n < 8; ++n) { f32x4 z = {0.f,0.f,0.f,0.f}; acc[n] = z; }
#pragma unroll
    for (int k0 = 0; k0 < 4; ++k0) {
      bf16x8 a = *(const bf16x8*)(&U[w16 + lr][k0 * 32 + lg * 8]);
#pragma unroll
      for (int n = 0; n < 8; ++n) {
        bf16x8 b = *(const bf16x8*)(N2b + ((n * 16 + lr) << 7) + k0 * 32 + lg * 8);
        acc[n] = __builtin_amdgcn_mfma_f32_16x16x32_bf16(a, b, acc[n], 0, 0, 0);
      }
    }
#pragma unroll
    for (int n = 0; n < 8; ++n) {
      int o = n * 16 + lr;
      float b2 = bn2[o];
#pragma unroll
      for (int r = 0; r < 4; ++r) {
        int me = w16 + lg * 4 + r;
        int ng = base + me; if (ng >= N) ng = N - 1;
        hp[(size_t)me * 132 + o] = acc[n][r] + b2 + h[(size_t)ng * 128 + o];
      }
    }
  }
  __syncthreads();

  {
    int r = tid >> 2, q = tid & 3;
    int ng = base + r;
    float s = 0.f, s2 = 0.f;
#pragma unroll
    for (int j = 0; j < 32; ++j) {
      float v = hp[(size_t)r * 132 + q * 32 + j];
      s += v; s2 += v * v;
    }
    s  += __shfl_xor(s, 1);  s  += __shfl_xor(s, 2);
    s2 += __shfl_xor(s2, 1); s2 += __shfl_xor(s2, 2);
    float mu  = s * (1.0f / 128.0f);
    float var = s2 * (1.0f / 128.0f) - mu * mu;
    float rs  = rsqrtf(var + 1e-5f);
    if (ng < N) {
#pragma unroll
      for (int j = 0; j < 32; ++j) {
        int o = q * 32 + j;
        float v = (hp[(size_t)r * 132 + o] - mu) * rs * gamma[o] + beta[o];
        aggH[(size_t)ng * 128 + o] = v;
      }
    }
  }

  if (tid < 192) {
    int i = tid / 3, c = tid % 3;
    int n2 = base + i;
    if (n2 < N) {
      size_t off = (size_t)n2 * 3 + c;
      coordX[off] = x[off] + coordX[off] / scnt[i];
    }
  }
}

extern "C" void kernel_launch(void* const* d_in, const int* in_sizes, int n_in,
                              void* d_out, int out_size, void* d_ws, size_t ws_size,
                              hipStream_t stream) {
  const float* h    = (const float*)d_in[0];
  const float* x    = (const float*)d_in[1];
  const int*   ei   = (const int*)d_in[2];
  const float* We1  = (const float*)d_in[3];
  const float* be1  = (const float*)d_in[4];
  const float* We2  = (const float*)d_in[5];
  const float* be2  = (const float*)d_in[6];
  const float* Wn1  = (const float*)d_in[7];
  const float* bn1  = (const float*)d_in[8];
  const float* Wn2  = (const float*)d_in[9];
  const float* bn2  = (const float*)d_in[10];
  const float* Wc1  = (const float*)d_in[11];
  const float* bc1  = (const float*)d_in[12];
  const float* Wc2  = (const float*)d_in[13];
  const float* gamma = (const float*)d_in[14];
  const float* beta  = (const float*)d_in[15];

  int N = in_sizes[0] / 128;
  int E = in_sizes[2] / 2;

  float* aggH   = (float*)d_out;                       // N*128: agg accumulator -> h_out
  float* coordX = (float*)d_out + (size_t)N * 128;     // N*3:   coord accumulator -> x_out

  char* ws = (char*)d_ws;
  size_t off = 0;
  auto alloc = [&](size_t bytes) {
    char* p = ws + off;
    off = (off + bytes + 255) & ~(size_t)255;
    return p;
  };
  unsigned short* PsPd   = (unsigned short*)alloc((size_t)N * 256 * 2);
  unsigned short* W1p    = (unsigned short*)alloc(256 * 128 * 2);
  unsigned short* W2b    = (unsigned short*)alloc(128 * 128 * 2);
  unsigned short* N1b    = (unsigned short*)alloc(128 * 256 * 2);
  unsigned short* N2b    = (unsigned short*)alloc(128 * 128 * 2);
  unsigned short* W3b    = (unsigned short*)alloc(128 * 128 * 2);
  float*          w1c    = (float*)alloc(128 * 4);
  int*            flag   = (int*)alloc(4);
  int*            deg    = (int*)alloc((size_t)N * 4);
  int*            offs   = (int*)alloc(((size_t)N + 1) * 4);
  int*            cursor = (int*)alloc((size_t)N * 4);
  int*            bsum   = (int*)alloc(256 * 4);
  int*            csr_e  = (int*)alloc((size_t)E * 4);
  (void)ws_size;

  int nb = (N + 255) / 256;   // N=50000 -> 196 (<=256 required by scanB)

  hipMemsetAsync(d_out, 0, (size_t)out_size * 4, stream);
  hipMemsetAsync(deg, 0, (size_t)N * 4, stream);

  prep_kernel<<<128, 256, 0, stream>>>(We1, We2, Wn1, Wn2, Wc1, ei,
                                       W1p, W2b, N1b, N2b, W3b, w1c, flag);
  hist_kernel<<<(E + 255) / 256, 256, 0, stream>>>(ei, flag, deg, E);
  scanA_kernel<<<nb, 256, 0, stream>>>(deg, offs, bsum, N);
  scanB_kernel<<<1, 256, 0, stream>>>(bsum, offs, nb, N);
  scanC_kernel<<<nb, 256, 0, stream>>>(bsum, offs, cursor, N);
  scatter_kernel<<<(E + 255) / 256, 256, 0, stream>>>(ei, flag, cursor, csr_e, E);
  proj_kernel<<<(N + 63) / 64, 256, 0, stream>>>(h, be1, W1p, PsPd, N);
  edge_kernel<<<(E + 63) / 64, 256, 0, stream>>>(PsPd, x, ei, w1c, be2, bc1, Wc2,
                                                 W2b, W3b, aggH, coordX, csr_e, flag, E);
  node_kernel<<<(N + 63) / 64, 256, 0, stream>>>(h, x, bn1, bn2, gamma, beta, N1b, N2b,
                                                 aggH, coordX, deg, N);
}